// Round 7
// baseline (815.565 us; speedup 1.0000x reference)
//
#include <hip/hip_runtime.h>
#include <math.h>

// B=128, N=64, D=2, H=64, M=64 (!), L=2. f32 in / f32 out (beacon-verified).
// Recompute strategy: he is never stored globally. Per (b,j) wave:
//   L0: g1 -> he0(=g1@ew2) -> z0(=p0+he0@w1he0, gelu) -> he0'(@w2_0)
//       -> a(@u1_0, gelu) -> S (mask i!=j) -> hv1[j] = hv0[j] + S@u2_0/63 + c2_0
//   L1: recompute he0' chain, then z1(p1,w1he1) -> he1(@w2_1) -> a(@u1_1)
//       -> S -> hv2 -> head MLP -> dx
// ws: hv0(2MB) hv1(2MB) p0(2MB) p1(2MB) dx(64KB)

__device__ __forceinline__ float gelu_f(float x) {
    float u = x * 0.70710678118654752f;
    float s = fabsf(u);
    float t = __builtin_amdgcn_rcpf(fmaf(0.3275911f, s, 1.0f));
    float P = t * fmaf(t, fmaf(t, fmaf(t, fmaf(t, 1.061405429f, -1.453152027f),
                                        1.421413741f), -0.284496736f), 0.254829592f);
    float e = __expf(-s * s);
    float r = fmaf(-P, e, 1.0f);          // erf(|u|), max err 1.5e-7
    r = copysignf(r, u);
    return 0.5f * x * (1.0f + r);
}

__device__ __forceinline__ void initB(float acc[8][8], const float* __restrict__ bias, int lk8) {
    float4 c0 = *(const float4*)(bias + lk8);
    float4 c1 = *(const float4*)(bias + lk8 + 4);
    float cv[8] = {c0.x,c0.y,c0.z,c0.w,c1.x,c1.y,c1.z,c1.w};
    #pragma unroll
    for (int ii = 0; ii < 8; ++ii)
        #pragma unroll
        for (int kk = 0; kk < 8; ++kk) acc[ii][kk] = cv[kk];
}

__device__ __forceinline__ void initP(float acc[8][8], const float* __restrict__ Prow, int lk8) {
    // Prow = p + (b*64 + li*8)*64 + lk8 ; row stride 64
    #pragma unroll
    for (int ii = 0; ii < 8; ++ii) {
        float4 c0 = *(const float4*)(Prow + ii*64);
        float4 c1 = *(const float4*)(Prow + ii*64 + 4);
        acc[ii][0]=c0.x; acc[ii][1]=c0.y; acc[ii][2]=c0.z; acc[ii][3]=c0.w;
        acc[ii][4]=c1.x; acc[ii][5]=c1.y; acc[ii][6]=c1.z; acc[ii][7]=c1.w;
    }
}

__device__ __forceinline__ void gemm64(const float* __restrict__ tile,
                                       const float* __restrict__ W,
                                       float acc[8][8], int li8, int lk8) {
    #pragma unroll 8
    for (int m = 0; m < 64; ++m) {
        float4 a0 = *(const float4*)(tile + m*64 + li8);
        float4 a1 = *(const float4*)(tile + m*64 + li8 + 4);
        float4 b0 = *(const float4*)(W + m*64 + lk8);
        float4 b1 = *(const float4*)(W + m*64 + lk8 + 4);
        float av[8] = {a0.x,a0.y,a0.z,a0.w,a1.x,a1.y,a1.z,a1.w};
        float bv[8] = {b0.x,b0.y,b0.z,b0.w,b1.x,b1.y,b1.z,b1.w};
        #pragma unroll
        for (int ii = 0; ii < 8; ++ii)
            #pragma unroll
            for (int kk = 0; kk < 8; ++kk)
                acc[ii][kk] = fmaf(av[ii], bv[kk], acc[ii][kk]);
    }
}

template<bool GELU>
__device__ __forceinline__ void storeT(float* __restrict__ tile, float acc[8][8],
                                       int li8, int lk) {
    // lane holds out[i=li8+ii][k=lk*8+kk]; store transposed -> tile[k][i]
    #pragma unroll
    for (int kk = 0; kk < 8; ++kk) {
        float v[8];
        #pragma unroll
        for (int ii = 0; ii < 8; ++ii)
            v[ii] = GELU ? gelu_f(acc[ii][kk]) : acc[ii][kk];
        *(float4*)(tile + (lk*8+kk)*64 + li8)     = make_float4(v[0],v[1],v[2],v[3]);
        *(float4*)(tile + (lk*8+kk)*64 + li8 + 4) = make_float4(v[4],v[5],v[6],v[7]);
    }
}

// builds tile[m][i] = g1 = gelu(feat(i,j) @ ew1 + eb1)
__device__ __forceinline__ void edge_init(float* __restrict__ tile,
    const float* __restrict__ x, const float* __restrict__ ew1,
    const float* __restrict__ eb1, int b, int j, int lane) {
    float2 xi = ((const float2*)x)[b*64 + lane];
    float2 xj = ((const float2*)x)[b*64 + j];
    float d0 = xj.x - xi.x, d1 = xj.y - xi.y;   // dr[b,i,j] = x_j - x_i
    float r2 = fmaf(d0, d0, d1*d1);
    float rr = sqrtf(r2 + 1e-12f);
    for (int m = 0; m < 64; ++m) {
        float z = fmaf(d0, ew1[m], fmaf(d1, ew1[64+m],
                  fmaf(rr, ew1[128+m], fmaf(r2, ew1[192+m], eb1[m]))));
        tile[m*64 + lane] = gelu_f(z);
    }
}

// a(in acc, gelu'd) -> masked sum over i -> S in scratch tile[4096..4159]
__device__ __forceinline__ void s_reduce(float* __restrict__ tile, float acc[8][8],
                                         int li, int lk, int j) {
    float S[8];
    #pragma unroll
    for (int kk = 0; kk < 8; ++kk) S[kk] = 0.f;
    #pragma unroll
    for (int ii = 0; ii < 8; ++ii) {
        int i = li*8 + ii;
        float w = (i == j) ? 0.f : 1.f;
        #pragma unroll
        for (int kk = 0; kk < 8; ++kk) S[kk] += w * gelu_f(acc[ii][kk]);
    }
    #pragma unroll
    for (int off = 8; off <= 32; off <<= 1)
        #pragma unroll
        for (int kk = 0; kk < 8; ++kk) S[kk] += __shfl_xor(S[kk], off);
    if (li == 0)
        #pragma unroll
        for (int kk = 0; kk < 8; ++kk) tile[4096 + lk*8 + kk] = S[kk];
}

// hv_node[b,n,h] = gelu([x,spin]@nw1+nb1)@nw2+nb2
__global__ __launch_bounds__(64) void k_node(
    const float* __restrict__ x, const float* __restrict__ spin,
    const float* __restrict__ nw1, const float* __restrict__ nb1,
    const float* __restrict__ nw2, const float* __restrict__ nb2,
    float* __restrict__ hv)
{
    __shared__ float a[64];
    int node = blockIdx.x, h = threadIdx.x;
    float2 xv = ((const float2*)x)[node];
    float sp = spin[node];
    float z = fmaf(xv.x, nw1[h], fmaf(xv.y, nw1[64+h], fmaf(sp, nw1[128+h], nb1[h])));
    a[h] = gelu_f(z);
    __syncthreads();
    float acc = nb2[h];
    for (int k = 0; k < 64; ++k) acc = fmaf(a[k], nw2[k*64+h], acc);
    hv[node*64+h] = acc;
}

// p[b,i,k] = b1[k] + sum_h hv[b,i,h] * w1[h*64+k]   (node part of v2e input)
__global__ __launch_bounds__(64) void k_p(
    const float* __restrict__ hv, const float* __restrict__ w1,
    const float* __restrict__ b1, float* __restrict__ p)
{
    __shared__ float hl[64];
    int node = blockIdx.x, k = threadIdx.x;
    hl[k] = hv[node*64 + k];
    __syncthreads();
    float acc = b1[k];
    for (int h = 0; h < 64; ++h) acc = fmaf(hl[h], w1[h*64+k], acc);
    p[node*64 + k] = acc;
}

__global__ __launch_bounds__(64) void k_L0(
    const float* __restrict__ x,
    const float* __restrict__ ew1, const float* __restrict__ eb1,
    const float* __restrict__ ew2, const float* __restrict__ eb2,
    const float* __restrict__ p0,  const float* __restrict__ w1he0,
    const float* __restrict__ w2_0, const float* __restrict__ b2_0,
    const float* __restrict__ u1_0, const float* __restrict__ c1_0,
    const float* __restrict__ u2_0, const float* __restrict__ c2_0,
    const float* __restrict__ hv0, float* __restrict__ hv1)
{
    __shared__ float tile[4160];
    int lane = threadIdx.x, li = lane>>3, lk = lane&7;
    int li8 = li*8, lk8 = lk*8;
    int b = blockIdx.x >> 6, j = blockIdx.x & 63;
    float acc[8][8];

    edge_init(tile, x, ew1, eb1, b, j, lane);
    // he0 = g1@ew2 + eb2
    initB(acc, eb2, lk8); gemm64(tile, ew2, acc, li8, lk8); storeT<false>(tile, acc, li8, lk);
    // z0 = p0 + he0@w1he0 -> gelu
    initP(acc, p0 + (b*64 + li8)*64 + lk8, lk8);
    gemm64(tile, w1he0, acc, li8, lk8); storeT<true>(tile, acc, li8, lk);
    // he0' = @w2_0 + b2_0
    initB(acc, b2_0, lk8); gemm64(tile, w2_0, acc, li8, lk8); storeT<false>(tile, acc, li8, lk);
    // a = gelu(@u1_0 + c1_0), masked sum over i
    initB(acc, c1_0, lk8); gemm64(tile, u1_0, acc, li8, lk8);
    s_reduce(tile, acc, li, lk, j);
    // hv1[j] = hv0[j] + (S@u2_0)/63 + c2_0
    float g = 0.f;
    for (int m = 0; m < 64; ++m) g = fmaf(tile[4096+m], u2_0[m*64 + lane], g);
    int o = (b*64 + j)*64 + lane;
    hv1[o] = hv0[o] + g*(1.0f/63.0f) + c2_0[lane];
}

__global__ __launch_bounds__(64) void k_L1(
    const float* __restrict__ x,
    const float* __restrict__ ew1, const float* __restrict__ eb1,
    const float* __restrict__ ew2, const float* __restrict__ eb2,
    const float* __restrict__ p0,  const float* __restrict__ w1he0,
    const float* __restrict__ w2_0, const float* __restrict__ b2_0,
    const float* __restrict__ p1,  const float* __restrict__ w1he1,
    const float* __restrict__ w2_1, const float* __restrict__ b2_1,
    const float* __restrict__ u1_1, const float* __restrict__ c1_1,
    const float* __restrict__ u2_1, const float* __restrict__ c2_1,
    const float* __restrict__ hv1,
    const float* __restrict__ hw1, const float* __restrict__ hb1,
    const float* __restrict__ hw2, const float* __restrict__ hb2,
    const float* __restrict__ scale, float* __restrict__ dx)
{
    __shared__ float tile[4160];
    int lane = threadIdx.x, li = lane>>3, lk = lane&7;
    int li8 = li*8, lk8 = lk*8;
    int b = blockIdx.x >> 6, j = blockIdx.x & 63;
    float acc[8][8];

    // recompute he0' chain (layer-0 params)
    edge_init(tile, x, ew1, eb1, b, j, lane);
    initB(acc, eb2, lk8); gemm64(tile, ew2, acc, li8, lk8); storeT<false>(tile, acc, li8, lk);
    initP(acc, p0 + (b*64 + li8)*64 + lk8, lk8);
    gemm64(tile, w1he0, acc, li8, lk8); storeT<true>(tile, acc, li8, lk);
    initB(acc, b2_0, lk8); gemm64(tile, w2_0, acc, li8, lk8); storeT<false>(tile, acc, li8, lk);
    // layer-1 v2e
    initP(acc, p1 + (b*64 + li8)*64 + lk8, lk8);
    gemm64(tile, w1he1, acc, li8, lk8); storeT<true>(tile, acc, li8, lk);
    initB(acc, b2_1, lk8); gemm64(tile, w2_1, acc, li8, lk8); storeT<false>(tile, acc, li8, lk);
    // layer-1 e2v
    initB(acc, c1_1, lk8); gemm64(tile, u1_1, acc, li8, lk8);
    s_reduce(tile, acc, li, lk, j);
    float g = 0.f;
    for (int m = 0; m < 64; ++m) g = fmaf(tile[4096+m], u2_1[m*64 + lane], g);
    float hv2 = hv1[(b*64 + j)*64 + lane] + g*(1.0f/63.0f) + c2_1[lane];
    // head: t1 = tanh(hv2@hw1+hb1); dx = t1@hw2+hb2, * softplus(scale)
    tile[4096 + lane] = hv2;                    // wave-local scratch, in-order LDS
    float t = hb1[lane];
    for (int m = 0; m < 64; ++m) t = fmaf(tile[4096+m], hw1[m*64 + lane], t);
    t = tanhf(t);
    float d0 = t * hw2[lane*2], d1 = t * hw2[lane*2 + 1];
    #pragma unroll
    for (int off = 1; off <= 32; off <<= 1) { d0 += __shfl_xor(d0, off); d1 += __shfl_xor(d1, off); }
    if (lane == 0) {
        float sp = log1pf(__expf(scale[0]));
        dx[(b*64 + j)*2 + 0] = (d0 + hb2[0]) * sp;
        dx[(b*64 + j)*2 + 1] = (d1 + hb2[1]) * sp;
    }
}

__global__ __launch_bounds__(64) void k_mean(
    const float* __restrict__ dx, float* __restrict__ out)
{
    __shared__ float s0[64], s1[64];
    int b = blockIdx.x, j = threadIdx.x;
    float2 d = ((const float2*)dx)[b*64 + j];
    s0[j] = d.x; s1[j] = d.y;
    __syncthreads();
    float m0 = 0.f, m1 = 0.f;
    for (int q = 0; q < 64; ++q) { m0 += s0[q]; m1 += s1[q]; }
    ((float2*)out)[b*64 + j] = make_float2(d.x - m0*(1.0f/64.0f), d.y - m1*(1.0f/64.0f));
}

__global__ void k_beacon(float* out, float code) { out[0] = code; }

extern "C" void kernel_launch(void* const* d_in, const int* in_sizes, int n_in,
                              void* d_out, int out_size, void* d_ws, size_t ws_size,
                              hipStream_t stream)
{
    static const int exp_sizes[23] = {
        16384, 8192, 192, 64, 4096, 64,       // x spin nw1 nb1 nw2 nb2
        256, 64, 4096, 64,                    // ew1 eb1 ew2 eb2   (M=64!)
        16384, 128, 8192, 128,                // v2e w1 b1 w2 b2
        8192, 128, 8192, 128,                 // e2v w1 b1 w2 b2
        4096, 64, 128, 2, 1                   // hw1 hb1 hw2 hb2 scale
    };
    int bad = -1;
    if (n_in != 23 || out_size != 16384 || ws_size < 9000000) bad = 99;
    else for (int i = 0; i < 23; ++i)
        if (in_sizes[i] != exp_sizes[i]) { bad = i; break; }
    if (bad >= 0) {
        float code = 2e6f + bad*1e4f + (bad < n_in && bad < 23 ? (float)(in_sizes[bad] % 10000) : 0.f);
        k_beacon<<<1, 1, 0, stream>>>((float*)d_out, code);
        return;
    }

    const float* x      = (const float*)d_in[0];
    const float* spin   = (const float*)d_in[1];
    const float* nw1    = (const float*)d_in[2];
    const float* nb1    = (const float*)d_in[3];
    const float* nw2    = (const float*)d_in[4];
    const float* nb2    = (const float*)d_in[5];
    const float* ew1    = (const float*)d_in[6];
    const float* eb1    = (const float*)d_in[7];
    const float* ew2    = (const float*)d_in[8];
    const float* eb2    = (const float*)d_in[9];
    const float* v2e_w1 = (const float*)d_in[10];
    const float* v2e_b1 = (const float*)d_in[11];
    const float* v2e_w2 = (const float*)d_in[12];
    const float* v2e_b2 = (const float*)d_in[13];
    const float* e2v_w1 = (const float*)d_in[14];
    const float* e2v_b1 = (const float*)d_in[15];
    const float* e2v_w2 = (const float*)d_in[16];
    const float* e2v_b2 = (const float*)d_in[17];
    const float* hw1    = (const float*)d_in[18];
    const float* hb1    = (const float*)d_in[19];
    const float* hw2    = (const float*)d_in[20];
    const float* hb2    = (const float*)d_in[21];
    const float* scale  = (const float*)d_in[22];

    float* hv0 = (float*)d_ws;            // 524288 f
    float* hv1 = hv0 + 524288;
    float* p0  = hv1 + 524288;
    float* p1  = p0  + 524288;
    float* dx  = p1  + 524288;            // 16384 f

    k_node<<<8192, 64, 0, stream>>>(x, spin, nw1, nb1, nw2, nb2, hv0);
    k_p<<<8192, 64, 0, stream>>>(hv0, v2e_w1, v2e_b1, p0);
    k_L0<<<8192, 64, 0, stream>>>(x, ew1, eb1, ew2, eb2,
        p0, v2e_w1 + 4096, v2e_w2, v2e_b2,
        e2v_w1, e2v_b1, e2v_w2, e2v_b2, hv0, hv1);
    k_p<<<8192, 64, 0, stream>>>(hv1, v2e_w1 + 8192, v2e_b1 + 64, p1);
    k_L1<<<8192, 64, 0, stream>>>(x, ew1, eb1, ew2, eb2,
        p0, v2e_w1 + 4096, v2e_w2, v2e_b2,
        p1, v2e_w1 + 12288, v2e_w2 + 4096, v2e_b2 + 64,
        e2v_w1 + 4096, e2v_b1 + 64, e2v_w2 + 4096, e2v_b2 + 64,
        hv1, hw1, hb1, hw2, hb2, scale, dx);
    k_mean<<<128, 64, 0, stream>>>(dx, (float*)d_out);
}

// Round 8
// 684.390 us; speedup vs baseline: 1.1917x; 1.1917x over previous
//
#include <hip/hip_runtime.h>
#include <math.h>

// B=128, N=64, D=2, H=64, M=64, L=2. f32 in / f32 out (beacon-verified R6, passed R7).
// R8: (1) materialize he0' (134MB ws) so k_L1 skips the layer-0 recompute;
//     (2) 256-thread blocks: 4 waves share one 64x64 tile (cols-split GEMM),
//         occupancy 9 -> ~24 waves/CU.
// Per-block (one j): tile[m][i] stages; GEMM out[i][c] = sum_m tile[m][i]*W[m][c];
// transposed store back to tile[c][i]. Wave w owns cols w*16..w*16+15;
// lane(li,lk): rows li*8+[0,8), cols w*16+lk*2+[0,2); acc[8][2].

__device__ __forceinline__ float gelu_f(float x) {
    float u = x * 0.70710678118654752f;
    float s = fabsf(u);
    float t = __builtin_amdgcn_rcpf(fmaf(0.3275911f, s, 1.0f));
    float P = t * fmaf(t, fmaf(t, fmaf(t, fmaf(t, 1.061405429f, -1.453152027f),
                                        1.421413741f), -0.284496736f), 0.254829592f);
    float e = __expf(-s * s);
    float r = fmaf(-P, e, 1.0f);          // erf(|u|), max err 1.5e-7
    r = copysignf(r, u);
    return 0.5f * x * (1.0f + r);
}

__device__ __forceinline__ void acc_bias(float acc[8][2], const float* __restrict__ bias, int c) {
    float2 bb = *(const float2*)(bias + c);
    #pragma unroll
    for (int ii = 0; ii < 8; ++ii) { acc[ii][0] = bb.x; acc[ii][1] = bb.y; }
}

__device__ __forceinline__ void acc_p(float acc[8][2], const float* __restrict__ P,
                                      int rowbase, int c) {
    #pragma unroll
    for (int ii = 0; ii < 8; ++ii) {
        float2 pv = *(const float2*)(P + (rowbase + ii) * 64 + c);
        acc[ii][0] = pv.x; acc[ii][1] = pv.y;
    }
}

__device__ __forceinline__ void stage_gemm(const float* __restrict__ tile,
                                           const float* __restrict__ W,
                                           float acc[8][2], int li8, int c) {
    #pragma unroll 8
    for (int m = 0; m < 64; ++m) {
        float4 a0 = *(const float4*)(tile + m * 64 + li8);
        float4 a1 = *(const float4*)(tile + m * 64 + li8 + 4);
        float2 bb = *(const float2*)(W + m * 64 + c);
        float av[8] = {a0.x, a0.y, a0.z, a0.w, a1.x, a1.y, a1.z, a1.w};
        #pragma unroll
        for (int ii = 0; ii < 8; ++ii) {
            acc[ii][0] = fmaf(av[ii], bb.x, acc[ii][0]);
            acc[ii][1] = fmaf(av[ii], bb.y, acc[ii][1]);
        }
    }
}

template<bool G>
__device__ __forceinline__ void store_t(float* __restrict__ tile, float acc[8][2],
                                        int li8, int c) {
    float v[2][8];
    #pragma unroll
    for (int ii = 0; ii < 8; ++ii) {
        v[0][ii] = G ? gelu_f(acc[ii][0]) : acc[ii][0];
        v[1][ii] = G ? gelu_f(acc[ii][1]) : acc[ii][1];
    }
    #pragma unroll
    for (int c2 = 0; c2 < 2; ++c2) {
        *(float4*)(tile + (c + c2) * 64 + li8)     = make_float4(v[c2][0], v[c2][1], v[c2][2], v[c2][3]);
        *(float4*)(tile + (c + c2) * 64 + li8 + 4) = make_float4(v[c2][4], v[c2][5], v[c2][6], v[c2][7]);
    }
}

// 256-thread edge init: tile[m][i] = gelu(feat(i,j) @ ew1 + eb1)
__device__ __forceinline__ void edge_init256(float* __restrict__ tile, float* __restrict__ sgeo,
    const float* __restrict__ x, const float* __restrict__ ew1, const float* __restrict__ eb1,
    int b, int j, int t) {
    if (t < 64) {
        float2 xi = ((const float2*)x)[b * 64 + t];
        float2 xj = ((const float2*)x)[b * 64 + j];
        float d0 = xj.x - xi.x, d1 = xj.y - xi.y;     // dr = x_j - x_i
        float r2 = fmaf(d0, d0, d1 * d1);
        sgeo[t] = d0; sgeo[64 + t] = d1; sgeo[128 + t] = sqrtf(r2 + 1e-12f); sgeo[192 + t] = r2;
    }
    __syncthreads();
    for (int q = t; q < 4096; q += 256) {
        int m = q >> 6, i = q & 63;
        float z = fmaf(sgeo[i], ew1[m], fmaf(sgeo[64 + i], ew1[64 + m],
                  fmaf(sgeo[128 + i], ew1[128 + m], fmaf(sgeo[192 + i], ew1[192 + m], eb1[m]))));
        tile[q] = gelu_f(z);
    }
    __syncthreads();
}

// layer-0 he chain: tile(g1) -> he0 -> gelu(p0 + he0@w1he0) -> he0' (in tile)
__device__ __forceinline__ void he_chain(float* __restrict__ tile,
    const float* __restrict__ ew2, const float* __restrict__ eb2,
    const float* __restrict__ p0, const float* __restrict__ w1he0,
    const float* __restrict__ w2_0, const float* __restrict__ b2_0,
    int b, int li8, int c) {
    float acc[8][2];
    acc_bias(acc, eb2, c); stage_gemm(tile, ew2, acc, li8, c);
    __syncthreads(); store_t<false>(tile, acc, li8, c); __syncthreads();
    acc_p(acc, p0, b * 64 + li8, c); stage_gemm(tile, w1he0, acc, li8, c);
    __syncthreads(); store_t<true>(tile, acc, li8, c); __syncthreads();
    acc_bias(acc, b2_0, c); stage_gemm(tile, w2_0, acc, li8, c);
    __syncthreads(); store_t<false>(tile, acc, li8, c); __syncthreads();
}

// v2e layer-1 part: gelu(p1 + tile@w1he1) @ w2_1 + b2_1 (in tile)
__device__ __forceinline__ void v2e_l1(float* __restrict__ tile,
    const float* __restrict__ p1, const float* __restrict__ w1he1,
    const float* __restrict__ w2_1, const float* __restrict__ b2_1,
    int b, int li8, int c) {
    float acc[8][2];
    acc_p(acc, p1, b * 64 + li8, c); stage_gemm(tile, w1he1, acc, li8, c);
    __syncthreads(); store_t<true>(tile, acc, li8, c); __syncthreads();
    acc_bias(acc, b2_1, c); stage_gemm(tile, w2_1, acc, li8, c);
    __syncthreads(); store_t<false>(tile, acc, li8, c); __syncthreads();
}

// e2v first layer + masked i-sum -> sS[64]
__device__ __forceinline__ void e2v_sum(const float* __restrict__ tile, float* __restrict__ sS,
    const float* __restrict__ u1, const float* __restrict__ c1,
    int li8, int c, int lane, int j) {
    float acc[8][2];
    acc_bias(acc, c1, c); stage_gemm(tile, u1, acc, li8, c);
    float s0 = 0.f, s1 = 0.f;
    #pragma unroll
    for (int ii = 0; ii < 8; ++ii) {
        int i = li8 + ii;
        if (i != j) { s0 += gelu_f(acc[ii][0]); s1 += gelu_f(acc[ii][1]); }
    }
    s0 += __shfl_xor(s0, 8);  s1 += __shfl_xor(s1, 8);
    s0 += __shfl_xor(s0, 16); s1 += __shfl_xor(s1, 16);
    s0 += __shfl_xor(s0, 32); s1 += __shfl_xor(s1, 32);
    if ((lane >> 3) == 0) { sS[c] = s0; sS[c + 1] = s1; }
    __syncthreads();
}

template<bool STORE_HE>
__global__ __launch_bounds__(256) void k_L0(
    const float* __restrict__ x,
    const float* __restrict__ ew1, const float* __restrict__ eb1,
    const float* __restrict__ ew2, const float* __restrict__ eb2,
    const float* __restrict__ p0,  const float* __restrict__ w1he0,
    const float* __restrict__ w2_0, const float* __restrict__ b2_0,
    const float* __restrict__ u1_0, const float* __restrict__ c1_0,
    const float* __restrict__ u2_0, const float* __restrict__ c2_0,
    const float* __restrict__ hv0, float* __restrict__ hv1,
    float* __restrict__ he0g)
{
    __shared__ float tile[4096];
    __shared__ float sgeo[256];
    __shared__ float sS[64];
    int t = threadIdx.x, w = t >> 6, lane = t & 63;
    int li8 = (lane >> 3) * 8, c = w * 16 + (lane & 7) * 2;
    int b = blockIdx.x >> 6, j = blockIdx.x & 63;

    edge_init256(tile, sgeo, x, ew1, eb1, b, j, t);
    he_chain(tile, ew2, eb2, p0, w1he0, w2_0, b2_0, b, li8, c);
    if (STORE_HE) {
        float4* dst = (float4*)(he0g + (size_t)blockIdx.x * 4096);
        const float4* src = (const float4*)tile;
        for (int q = t; q < 1024; q += 256) dst[q] = src[q];
    }
    e2v_sum(tile, sS, u1_0, c1_0, li8, c, lane, j);
    if (t < 64) {
        float g = 0.f;
        for (int m = 0; m < 64; ++m) g = fmaf(sS[m], u2_0[m * 64 + t], g);
        int o = blockIdx.x * 64 + t;
        hv1[o] = hv0[o] + g * (1.0f / 63.0f) + c2_0[t];
    }
}

__device__ __forceinline__ void l1_tail(const float* __restrict__ tile, float* __restrict__ sS,
    float* __restrict__ shv,
    const float* __restrict__ u1_1, const float* __restrict__ c1_1,
    const float* __restrict__ u2_1, const float* __restrict__ c2_1,
    const float* __restrict__ hv1,
    const float* __restrict__ hw1, const float* __restrict__ hb1,
    const float* __restrict__ hw2, const float* __restrict__ hb2,
    const float* __restrict__ scale, float* __restrict__ dx,
    int li8, int c, int lane, int j, int t, int blk)
{
    e2v_sum(tile, sS, u1_1, c1_1, li8, c, lane, j);
    if (t < 64) {
        float g = 0.f;
        for (int m = 0; m < 64; ++m) g = fmaf(sS[m], u2_1[m * 64 + t], g);
        float hv2 = hv1[blk * 64 + t] + g * (1.0f / 63.0f) + c2_1[t];
        shv[t] = hv2;                      // wave-synchronous LDS use (wave 0 only)
        float a = hb1[t];
        for (int m = 0; m < 64; ++m) a = fmaf(shv[m], hw1[m * 64 + t], a);
        float t1 = tanhf(a);
        float d0 = t1 * hw2[t * 2], d1 = t1 * hw2[t * 2 + 1];
        #pragma unroll
        for (int off = 1; off <= 32; off <<= 1) { d0 += __shfl_xor(d0, off); d1 += __shfl_xor(d1, off); }
        if (t == 0) {
            float sp = log1pf(__expf(scale[0]));
            dx[blk * 2 + 0] = (d0 + hb2[0]) * sp;
            dx[blk * 2 + 1] = (d1 + hb2[1]) * sp;
        }
    }
}

__global__ __launch_bounds__(256) void k_L1_load(
    const float* __restrict__ he0g,
    const float* __restrict__ p1,  const float* __restrict__ w1he1,
    const float* __restrict__ w2_1, const float* __restrict__ b2_1,
    const float* __restrict__ u1_1, const float* __restrict__ c1_1,
    const float* __restrict__ u2_1, const float* __restrict__ c2_1,
    const float* __restrict__ hv1,
    const float* __restrict__ hw1, const float* __restrict__ hb1,
    const float* __restrict__ hw2, const float* __restrict__ hb2,
    const float* __restrict__ scale, float* __restrict__ dx)
{
    __shared__ float tile[4096];
    __shared__ float sS[64];
    __shared__ float shv[64];
    int t = threadIdx.x, w = t >> 6, lane = t & 63;
    int li8 = (lane >> 3) * 8, c = w * 16 + (lane & 7) * 2;
    int b = blockIdx.x >> 6, j = blockIdx.x & 63;

    {
        const float4* src = (const float4*)(he0g + (size_t)blockIdx.x * 4096);
        float4* dst = (float4*)tile;
        for (int q = t; q < 1024; q += 256) dst[q] = src[q];
    }
    __syncthreads();
    v2e_l1(tile, p1, w1he1, w2_1, b2_1, b, li8, c);
    l1_tail(tile, sS, shv, u1_1, c1_1, u2_1, c2_1, hv1,
            hw1, hb1, hw2, hb2, scale, dx, li8, c, lane, j, t, blockIdx.x);
}

__global__ __launch_bounds__(256) void k_L1_rec(
    const float* __restrict__ x,
    const float* __restrict__ ew1, const float* __restrict__ eb1,
    const float* __restrict__ ew2, const float* __restrict__ eb2,
    const float* __restrict__ p0,  const float* __restrict__ w1he0,
    const float* __restrict__ w2_0, const float* __restrict__ b2_0,
    const float* __restrict__ p1,  const float* __restrict__ w1he1,
    const float* __restrict__ w2_1, const float* __restrict__ b2_1,
    const float* __restrict__ u1_1, const float* __restrict__ c1_1,
    const float* __restrict__ u2_1, const float* __restrict__ c2_1,
    const float* __restrict__ hv1,
    const float* __restrict__ hw1, const float* __restrict__ hb1,
    const float* __restrict__ hw2, const float* __restrict__ hb2,
    const float* __restrict__ scale, float* __restrict__ dx)
{
    __shared__ float tile[4096];
    __shared__ float sgeo[256];
    __shared__ float sS[64];
    __shared__ float shv[64];
    int t = threadIdx.x, w = t >> 6, lane = t & 63;
    int li8 = (lane >> 3) * 8, c = w * 16 + (lane & 7) * 2;
    int b = blockIdx.x >> 6, j = blockIdx.x & 63;

    edge_init256(tile, sgeo, x, ew1, eb1, b, j, t);
    he_chain(tile, ew2, eb2, p0, w1he0, w2_0, b2_0, b, li8, c);
    v2e_l1(tile, p1, w1he1, w2_1, b2_1, b, li8, c);
    l1_tail(tile, sS, shv, u1_1, c1_1, u2_1, c2_1, hv1,
            hw1, hb1, hw2, hb2, scale, dx, li8, c, lane, j, t, blockIdx.x);
}

// hv[b,n,h] = gelu([x,spin]@nw1+nb1)@nw2+nb2   (proven R7)
__global__ __launch_bounds__(64) void k_node(
    const float* __restrict__ x, const float* __restrict__ spin,
    const float* __restrict__ nw1, const float* __restrict__ nb1,
    const float* __restrict__ nw2, const float* __restrict__ nb2,
    float* __restrict__ hv)
{
    __shared__ float a[64];
    int node = blockIdx.x, h = threadIdx.x;
    float2 xv = ((const float2*)x)[node];
    float sp = spin[node];
    float z = fmaf(xv.x, nw1[h], fmaf(xv.y, nw1[64 + h], fmaf(sp, nw1[128 + h], nb1[h])));
    a[h] = gelu_f(z);
    __syncthreads();
    float acc = nb2[h];
    for (int k = 0; k < 64; ++k) acc = fmaf(a[k], nw2[k * 64 + h], acc);
    hv[node * 64 + h] = acc;
}

// p[b,i,k] = b1[k] + sum_h hv[b,i,h] * w1[h*64+k]   (proven R7)
__global__ __launch_bounds__(64) void k_p(
    const float* __restrict__ hv, const float* __restrict__ w1,
    const float* __restrict__ b1, float* __restrict__ p)
{
    __shared__ float hl[64];
    int node = blockIdx.x, k = threadIdx.x;
    hl[k] = hv[node * 64 + k];
    __syncthreads();
    float acc = b1[k];
    for (int h = 0; h < 64; ++h) acc = fmaf(hl[h], w1[h * 64 + k], acc);
    p[node * 64 + k] = acc;
}

__global__ __launch_bounds__(64) void k_mean(
    const float* __restrict__ dx, float* __restrict__ out)
{
    __shared__ float s0[64], s1[64];
    int b = blockIdx.x, j = threadIdx.x;
    float2 d = ((const float2*)dx)[b * 64 + j];
    s0[j] = d.x; s1[j] = d.y;
    __syncthreads();
    float m0 = 0.f, m1 = 0.f;
    for (int q = 0; q < 64; ++q) { m0 += s0[q]; m1 += s1[q]; }
    ((float2*)out)[b * 64 + j] = make_float2(d.x - m0 * (1.0f / 64.0f), d.y - m1 * (1.0f / 64.0f));
}

__global__ void k_beacon(float* out, float code) { out[0] = code; }

extern "C" void kernel_launch(void* const* d_in, const int* in_sizes, int n_in,
                              void* d_out, int out_size, void* d_ws, size_t ws_size,
                              hipStream_t stream)
{
    static const int exp_sizes[23] = {
        16384, 8192, 192, 64, 4096, 64,
        256, 64, 4096, 64,
        16384, 128, 8192, 128,
        8192, 128, 8192, 128,
        4096, 64, 128, 2, 1
    };
    int bad = -1;
    if (n_in != 23 || out_size != 16384 || ws_size < 9000000) bad = 99;
    else for (int i = 0; i < 23; ++i)
        if (in_sizes[i] != exp_sizes[i]) { bad = i; break; }
    if (bad >= 0) {
        float code = 2e6f + bad * 1e4f;
        k_beacon<<<1, 1, 0, stream>>>((float*)d_out, code);
        return;
    }

    const float* x      = (const float*)d_in[0];
    const float* spin   = (const float*)d_in[1];
    const float* nw1    = (const float*)d_in[2];
    const float* nb1    = (const float*)d_in[3];
    const float* nw2    = (const float*)d_in[4];
    const float* nb2    = (const float*)d_in[5];
    const float* ew1    = (const float*)d_in[6];
    const float* eb1    = (const float*)d_in[7];
    const float* ew2    = (const float*)d_in[8];
    const float* eb2    = (const float*)d_in[9];
    const float* v2e_w1 = (const float*)d_in[10];
    const float* v2e_b1 = (const float*)d_in[11];
    const float* v2e_w2 = (const float*)d_in[12];
    const float* v2e_b2 = (const float*)d_in[13];
    const float* e2v_w1 = (const float*)d_in[14];
    const float* e2v_b1 = (const float*)d_in[15];
    const float* e2v_w2 = (const float*)d_in[16];
    const float* e2v_b2 = (const float*)d_in[17];
    const float* hw1    = (const float*)d_in[18];
    const float* hb1    = (const float*)d_in[19];
    const float* hw2    = (const float*)d_in[20];
    const float* hb2    = (const float*)d_in[21];
    const float* scale  = (const float*)d_in[22];

    float* hv0 = (float*)d_ws;            // 524288 f
    float* hv1 = hv0 + 524288;
    float* p0  = hv1 + 524288;
    float* p1  = p0  + 524288;
    float* dx  = p1  + 524288;            // 16384 f
    float* he0g = dx + 16384;             // 33554432 f (134.2 MB)
    const size_t need_mat = (size_t)(524288ull * 4 + 16384 + 33554432ull) * 4ull;  // ~142.7 MB
    const bool mat = ws_size >= need_mat; // constant per environment -> same work every call

    k_node<<<8192, 64, 0, stream>>>(x, spin, nw1, nb1, nw2, nb2, hv0);
    k_p<<<8192, 64, 0, stream>>>(hv0, v2e_w1, v2e_b1, p0);
    if (mat)
        k_L0<true><<<8192, 256, 0, stream>>>(x, ew1, eb1, ew2, eb2,
            p0, v2e_w1 + 4096, v2e_w2, v2e_b2,
            e2v_w1, e2v_b1, e2v_w2, e2v_b2, hv0, hv1, he0g);
    else
        k_L0<false><<<8192, 256, 0, stream>>>(x, ew1, eb1, ew2, eb2,
            p0, v2e_w1 + 4096, v2e_w2, v2e_b2,
            e2v_w1, e2v_b1, e2v_w2, e2v_b2, hv0, hv1, he0g);
    k_p<<<8192, 64, 0, stream>>>(hv1, v2e_w1 + 8192, v2e_b1 + 64, p1);
    if (mat)
        k_L1_load<<<8192, 256, 0, stream>>>(he0g,
            p1, v2e_w1 + 12288, v2e_w2 + 4096, v2e_b2 + 64,
            e2v_w1 + 4096, e2v_b1 + 64, e2v_w2 + 4096, e2v_b2 + 64,
            hv1, hw1, hb1, hw2, hb2, scale, dx);
    else
        k_L1_rec<<<8192, 256, 0, stream>>>(x, ew1, eb1, ew2, eb2,
            p0, v2e_w1 + 4096, v2e_w2, v2e_b2,
            p1, v2e_w1 + 12288, v2e_w2 + 4096, v2e_b2 + 64,
            e2v_w1 + 4096, e2v_b1 + 64, e2v_w2 + 4096, e2v_b2 + 64,
            hv1, hw1, hb1, hw2, hb2, scale, dx);
    k_mean<<<128, 64, 0, stream>>>(dx, (float*)d_out);
}

// Round 9
// 314.651 us; speedup vs baseline: 2.5920x; 2.1751x over previous
//
#include <hip/hip_runtime.h>
#include <math.h>

// B=128, N=64, D=2, H=64, M=64, L=2. f32 in / f32 out (beacon-verified R6; R7/R8 passed).
// R9: all seven 64x64 stage-GEMMs -> v_mfma_f32_16x16x32_bf16 with split-bf16
// (x = hi + lo; A*B ~= AhBh + AhBl + AlBh). Tile in LDS as hi/lo bf16 [64][72],
// XOR-swizzled k-blocks. Weights pre-packed once (k_prep_w) into B-frag order.
// he0' stored packed (hi<<16|lo) in ws (134MB) so k_L1 skips the layer-0 chain.

typedef unsigned short u16;
typedef unsigned int u32;
typedef __attribute__((ext_vector_type(8))) short short8;   // bf16x8 frag (4 VGPR)
typedef __attribute__((ext_vector_type(4))) float floatx4;  // f32x4 acc

#define TS 72   // tile row stride (bf16 elems): 144 B, 16B-aligned rows

__device__ __forceinline__ u16 f2bf(float f) {
    union { float f; u32 u; } v; v.f = f;
    u32 r = v.u + 0x7FFFu + ((v.u >> 16) & 1u);   // RNE
    return (u16)(r >> 16);
}
__device__ __forceinline__ float bf2f(u16 h) {
    union { u32 u; float f; } v; v.u = ((u32)h) << 16; return v.f;
}
__device__ __forceinline__ void split(float f, u16& h, u16& l) {
    h = f2bf(f); l = f2bf(f - bf2f(h));
}

__device__ __forceinline__ float gelu_f(float x) {
    float u = x * 0.70710678118654752f;
    float s = fabsf(u);
    float t = __builtin_amdgcn_rcpf(fmaf(0.3275911f, s, 1.0f));
    float P = t * fmaf(t, fmaf(t, fmaf(t, fmaf(t, 1.061405429f, -1.453152027f),
                                        1.421413741f), -0.284496736f), 0.254829592f);
    float e = __expf(-s * s);
    float r = fmaf(-P, e, 1.0f);          // erf(|u|), max err 1.5e-7
    r = copysignf(r, u);
    return 0.5f * x * (1.0f + r);
}

// pack 7 stage-weights (64x64 each) into B-fragment order, hi/lo bf16:
// off = (((s*2+kc)*64 + n)*4 + q)*8 + j  where k = kc*32 + q*8 + j
__global__ __launch_bounds__(256) void k_prep_w(
    const float* w0, const float* w1, const float* w2, const float* w3,
    const float* w4, const float* w5, const float* w6,
    u16* __restrict__ WH, u16* __restrict__ WL)
{
    int idx = blockIdx.x * 256 + threadIdx.x;
    if (idx >= 7 * 4096) return;
    int s = idx >> 12, r = idx & 4095, k = r >> 6, n = r & 63;
    const float* W = s==0?w0: s==1?w1: s==2?w2: s==3?w3: s==4?w4: s==5?w5: w6;
    u16 h, l; split(W[k * 64 + n], h, l);
    int kc = k >> 5, q = (k >> 3) & 3, jj = k & 7;
    int off = (((s * 2 + kc) * 64 + n) * 4 + q) * 8 + jj;
    WH[off] = h; WL[off] = l;
}

// wave computes out[0:64][c0:c0+16] for one 64x64 GEMM stage.
// acc[mt] holds rows mt*16+quad*4+[0,4), col c0+(lane&15).
__device__ __forceinline__ void mfma_stage(
    const u16* __restrict__ tH, const u16* __restrict__ tL,
    const u16* __restrict__ WH, const u16* __restrict__ WL,
    int stage, int c, int quad, int nn, floatx4 acc[4])
{
    #pragma unroll
    for (int mt = 0; mt < 4; ++mt) acc[mt] = (floatx4){0.f, 0.f, 0.f, 0.f};
    int sA = ((nn >> 2) & 3) << 3;        // row-swizzle for A rows (mt*16+nn)
    #pragma unroll
    for (int kc = 0; kc < 2; ++kc) {
        int woff = (((stage * 2 + kc) * 64 + c) * 4 + quad) * 8;
        short8 bh = *(const short8*)(WH + woff);
        short8 bl = *(const short8*)(WL + woff);
        int k0 = (kc * 32 + quad * 8) ^ sA;
        #pragma unroll
        for (int mt = 0; mt < 4; ++mt) {
            int aoff = (mt * 16 + nn) * TS + k0;
            short8 ah = *(const short8*)(tH + aoff);
            short8 al = *(const short8*)(tL + aoff);
            acc[mt] = __builtin_amdgcn_mfma_f32_16x16x32_bf16(ah, bh, acc[mt], 0, 0, 0);
            acc[mt] = __builtin_amdgcn_mfma_f32_16x16x32_bf16(ah, bl, acc[mt], 0, 0, 0);
            acc[mt] = __builtin_amdgcn_mfma_f32_16x16x32_bf16(al, bh, acc[mt], 0, 0, 0);
        }
    }
}

__global__ __launch_bounds__(256, 4) void k_L0(
    const float* __restrict__ x,
    const float* __restrict__ ew1, const float* __restrict__ eb1,
    const float* __restrict__ eb2,
    const float* __restrict__ p0, const float* __restrict__ b2_0,
    const float* __restrict__ c1_0,
    const float* __restrict__ u2_0, const float* __restrict__ c2_0,
    const u16* __restrict__ WH, const u16* __restrict__ WL,
    const float* __restrict__ hv0, float* __restrict__ hv1,
    u32* __restrict__ he0g)
{
    __shared__ __align__(16) u16 tH[64 * TS];
    __shared__ __align__(16) u16 tL[64 * TS];
    __shared__ float sgeo[256];
    __shared__ float sS[64];
    int t = threadIdx.x, w = t >> 6, L = t & 63;
    int nn = L & 15, quad = L >> 4;
    int c = w * 16 + nn;
    int sW = quad << 3;                    // write-swizzle (rows mt*16+quad*4+r)
    int b = blockIdx.x >> 6, j = blockIdx.x & 63;

    if (t < 64) {
        float2 xi = ((const float2*)x)[b * 64 + t];
        float2 xj = ((const float2*)x)[b * 64 + j];
        float d0 = xj.x - xi.x, d1 = xj.y - xi.y;     // dr = x_j - x_i
        float r2 = fmaf(d0, d0, d1 * d1);
        sgeo[t] = d0; sgeo[64 + t] = d1; sgeo[128 + t] = sqrtf(r2 + 1e-12f); sgeo[192 + t] = r2;
    }
    __syncthreads();
    // g1[i][m] = gelu(feat(i) @ ew1 + eb1)
    for (int q = t; q < 4096; q += 256) {
        int i = q >> 6, m = q & 63;
        float z = fmaf(sgeo[i], ew1[m], fmaf(sgeo[64 + i], ew1[64 + m],
                  fmaf(sgeo[128 + i], ew1[128 + m], fmaf(sgeo[192 + i], ew1[192 + m], eb1[m]))));
        u16 h, l; split(gelu_f(z), h, l);
        int mm = m ^ (((i >> 2) & 3) << 3);
        tH[i * TS + mm] = h; tL[i * TS + mm] = l;
    }
    __syncthreads();

    floatx4 acc[4];
    // stage 0: he0 = g1 @ ew2 + eb2
    mfma_stage(tH, tL, WH, WL, 0, c, quad, nn, acc);
    __syncthreads();
    {
        float bc = eb2[c];
        int cw = c ^ sW;
        #pragma unroll
        for (int mt = 0; mt < 4; ++mt)
            #pragma unroll
            for (int r = 0; r < 4; ++r) {
                int i = mt * 16 + quad * 4 + r;
                u16 h, l; split(acc[mt][r] + bc, h, l);
                tH[i * TS + cw] = h; tL[i * TS + cw] = l;
            }
    }
    __syncthreads();
    // stage 1: z0 = p0 + he0 @ w1he0 -> gelu
    mfma_stage(tH, tL, WH, WL, 1, c, quad, nn, acc);
    __syncthreads();
    {
        int cw = c ^ sW;
        #pragma unroll
        for (int mt = 0; mt < 4; ++mt)
            #pragma unroll
            for (int r = 0; r < 4; ++r) {
                int i = mt * 16 + quad * 4 + r;
                u16 h, l; split(gelu_f(acc[mt][r] + p0[(b * 64 + i) * 64 + c]), h, l);
                tH[i * TS + cw] = h; tL[i * TS + cw] = l;
            }
    }
    __syncthreads();
    // stage 2: he0' = @ w2_0 + b2_0 ; also store packed to global for k_L1
    mfma_stage(tH, tL, WH, WL, 2, c, quad, nn, acc);
    __syncthreads();
    {
        float bc = b2_0[c];
        int cw = c ^ sW;
        u32* dst = he0g + (size_t)blockIdx.x * 4096;
        #pragma unroll
        for (int mt = 0; mt < 4; ++mt)
            #pragma unroll
            for (int r = 0; r < 4; ++r) {
                int i = mt * 16 + quad * 4 + r;
                u16 h, l; split(acc[mt][r] + bc, h, l);
                tH[i * TS + cw] = h; tL[i * TS + cw] = l;
                dst[i * 64 + c] = ((u32)h << 16) | l;
            }
    }
    __syncthreads();
    // stage 3: a = gelu(@ u1_0 + c1_0); masked sum over i -> sS
    mfma_stage(tH, tL, WH, WL, 3, c, quad, nn, acc);
    {
        float bc = c1_0[c];
        float s = 0.f;
        #pragma unroll
        for (int mt = 0; mt < 4; ++mt)
            #pragma unroll
            for (int r = 0; r < 4; ++r) {
                int i = mt * 16 + quad * 4 + r;
                float g = gelu_f(acc[mt][r] + bc);
                s += (i == j) ? 0.f : g;
            }
        s += __shfl_xor(s, 16);
        s += __shfl_xor(s, 32);
        if (quad == 0) sS[c] = s;
    }
    __syncthreads();
    if (t < 64) {
        float g = 0.f;
        for (int m = 0; m < 64; ++m) g = fmaf(sS[m], u2_0[m * 64 + t], g);
        int o = blockIdx.x * 64 + t;
        hv1[o] = hv0[o] + g * (1.0f / 63.0f) + c2_0[t];
    }
}

__global__ __launch_bounds__(256, 4) void k_L1(
    const u32* __restrict__ he0g,
    const float* __restrict__ p1, const float* __restrict__ b2_1,
    const float* __restrict__ c1_1,
    const float* __restrict__ u2_1, const float* __restrict__ c2_1,
    const u16* __restrict__ WH, const u16* __restrict__ WL,
    const float* __restrict__ hv1,
    const float* __restrict__ hw1, const float* __restrict__ hb1,
    const float* __restrict__ hw2, const float* __restrict__ hb2,
    const float* __restrict__ scale, float* __restrict__ dx)
{
    __shared__ __align__(16) u16 tH[64 * TS];
    __shared__ __align__(16) u16 tL[64 * TS];
    __shared__ float sS[64];
    __shared__ float shv[64];
    int t = threadIdx.x, w = t >> 6, L = t & 63;
    int nn = L & 15, quad = L >> 4;
    int c = w * 16 + nn;
    int sW = quad << 3;
    int b = blockIdx.x >> 6, j = blockIdx.x & 63;

    {   // unpack he0' (hi<<16|lo)
        const u32* src = he0g + (size_t)blockIdx.x * 4096;
        for (int q = t; q < 4096; q += 256) {
            u32 u = src[q];
            int i = q >> 6, m = q & 63;
            int mm = m ^ (((i >> 2) & 3) << 3);
            tH[i * TS + mm] = (u16)(u >> 16);
            tL[i * TS + mm] = (u16)(u & 0xffffu);
        }
    }
    __syncthreads();

    floatx4 acc[4];
    // stage 4: z1 = p1 + he0' @ w1he1 -> gelu
    mfma_stage(tH, tL, WH, WL, 4, c, quad, nn, acc);
    __syncthreads();
    {
        int cw = c ^ sW;
        #pragma unroll
        for (int mt = 0; mt < 4; ++mt)
            #pragma unroll
            for (int r = 0; r < 4; ++r) {
                int i = mt * 16 + quad * 4 + r;
                u16 h, l; split(gelu_f(acc[mt][r] + p1[(b * 64 + i) * 64 + c]), h, l);
                tH[i * TS + cw] = h; tL[i * TS + cw] = l;
            }
    }
    __syncthreads();
    // stage 5: he1 = @ w2_1 + b2_1
    mfma_stage(tH, tL, WH, WL, 5, c, quad, nn, acc);
    __syncthreads();
    {
        float bc = b2_1[c];
        int cw = c ^ sW;
        #pragma unroll
        for (int mt = 0; mt < 4; ++mt)
            #pragma unroll
            for (int r = 0; r < 4; ++r) {
                int i = mt * 16 + quad * 4 + r;
                u16 h, l; split(acc[mt][r] + bc, h, l);
                tH[i * TS + cw] = h; tL[i * TS + cw] = l;
            }
    }
    __syncthreads();
    // stage 6: a = gelu(@ u1_1 + c1_1); masked sum -> sS
    mfma_stage(tH, tL, WH, WL, 6, c, quad, nn, acc);
    {
        float bc = c1_1[c];
        float s = 0.f;
        #pragma unroll
        for (int mt = 0; mt < 4; ++mt)
            #pragma unroll
            for (int r = 0; r < 4; ++r) {
                int i = mt * 16 + quad * 4 + r;
                float g = gelu_f(acc[mt][r] + bc);
                s += (i == j) ? 0.f : g;
            }
        s += __shfl_xor(s, 16);
        s += __shfl_xor(s, 32);
        if (quad == 0) sS[c] = s;
    }
    __syncthreads();
    if (t < 64) {
        float g = 0.f;
        for (int m = 0; m < 64; ++m) g = fmaf(sS[m], u2_1[m * 64 + t], g);
        float hv2 = hv1[blockIdx.x * 64 + t] + g * (1.0f / 63.0f) + c2_1[t];
        shv[t] = hv2;                        // wave-synchronous LDS (wave 0 only, proven R8)
        float a = hb1[t];
        for (int m = 0; m < 64; ++m) a = fmaf(shv[m], hw1[m * 64 + t], a);
        float t1 = tanhf(a);
        float d0 = t1 * hw2[t * 2], d1 = t1 * hw2[t * 2 + 1];
        #pragma unroll
        for (int off = 1; off <= 32; off <<= 1) { d0 += __shfl_xor(d0, off); d1 += __shfl_xor(d1, off); }
        if (t == 0) {
            float sp = log1pf(__expf(scale[0]));
            dx[blockIdx.x * 2 + 0] = (d0 + hb2[0]) * sp;
            dx[blockIdx.x * 2 + 1] = (d1 + hb2[1]) * sp;
        }
    }
}

// hv[b,n,h] = gelu([x,spin]@nw1+nb1)@nw2+nb2   (proven R7)
__global__ __launch_bounds__(64) void k_node(
    const float* __restrict__ x, const float* __restrict__ spin,
    const float* __restrict__ nw1, const float* __restrict__ nb1,
    const float* __restrict__ nw2, const float* __restrict__ nb2,
    float* __restrict__ hv)
{
    __shared__ float a[64];
    int node = blockIdx.x, h = threadIdx.x;
    float2 xv = ((const float2*)x)[node];
    float sp = spin[node];
    float z = fmaf(xv.x, nw1[h], fmaf(xv.y, nw1[64 + h], fmaf(sp, nw1[128 + h], nb1[h])));
    a[h] = gelu_f(z);
    __syncthreads();
    float acc = nb2[h];
    for (int k = 0; k < 64; ++k) acc = fmaf(a[k], nw2[k * 64 + h], acc);
    hv[node * 64 + h] = acc;
}

// p[b,i,k] = b1[k] + sum_h hv[b,i,h] * w1[h*64+k]   (proven R7)
__global__ __launch_bounds__(64) void k_p(
    const float* __restrict__ hv, const float* __restrict__ w1,
    const float* __restrict__ b1, float* __restrict__ p)
{
    __shared__ float hl[64];
    int node = blockIdx.x, k = threadIdx.x;
    hl[k] = hv[node * 64 + k];
    __syncthreads();
    float acc = b1[k];
    for (int h = 0; h < 64; ++h) acc = fmaf(hl[h], w1[h * 64 + k], acc);
    p[node * 64 + k] = acc;
}

__global__ __launch_bounds__(64) void k_mean(
    const float* __restrict__ dx, float* __restrict__ out)
{
    __shared__ float s0[64], s1[64];
    int b = blockIdx.x, j = threadIdx.x;
    float2 d = ((const float2*)dx)[b * 64 + j];
    s0[j] = d.x; s1[j] = d.y;
    __syncthreads();
    float m0 = 0.f, m1 = 0.f;
    for (int q = 0; q < 64; ++q) { m0 += s0[q]; m1 += s1[q]; }
    ((float2*)out)[b * 64 + j] = make_float2(d.x - m0 * (1.0f / 64.0f), d.y - m1 * (1.0f / 64.0f));
}

__global__ void k_beacon(float* out, float code) { out[0] = code; }

extern "C" void kernel_launch(void* const* d_in, const int* in_sizes, int n_in,
                              void* d_out, int out_size, void* d_ws, size_t ws_size,
                              hipStream_t stream)
{
    static const int exp_sizes[23] = {
        16384, 8192, 192, 64, 4096, 64,
        256, 64, 4096, 64,
        16384, 128, 8192, 128,
        8192, 128, 8192, 128,
        4096, 64, 128, 2, 1
    };
    // ws layout
    float* hv0 = (float*)d_ws;                  // 524288 f
    float* hv1 = hv0 + 524288;
    float* p0  = hv1 + 524288;
    float* p1  = p0  + 524288;
    float* dx  = p1  + 524288;                  // 16384 f
    u16* WH    = (u16*)(dx + 16384);            // 28672 u16
    u16* WL    = WH + 28672;
    u32* he0g  = (u32*)(WL + 28672);            // 33554432 u32
    const size_t need = (size_t)((char*)(he0g + 33554432) - (char*)d_ws);  // ~142.8 MB

    int bad = -1;
    if (n_in != 23 || out_size != 16384) bad = 98;
    else if (ws_size < need) bad = 97;
    else for (int i = 0; i < 23; ++i)
        if (in_sizes[i] != exp_sizes[i]) { bad = i; break; }
    if (bad >= 0) {
        k_beacon<<<1, 1, 0, stream>>>((float*)d_out, 2e6f + bad * 1e4f);
        return;
    }

    const float* x      = (const float*)d_in[0];
    const float* spin   = (const float*)d_in[1];
    const float* nw1    = (const float*)d_in[2];
    const float* nb1    = (const float*)d_in[3];
    const float* nw2    = (const float*)d_in[4];
    const float* nb2    = (const float*)d_in[5];
    const float* ew1    = (const float*)d_in[6];
    const float* eb1    = (const float*)d_in[7];
    const float* ew2    = (const float*)d_in[8];
    const float* eb2    = (const float*)d_in[9];
    const float* v2e_w1 = (const float*)d_in[10];
    const float* v2e_b1 = (const float*)d_in[11];
    const float* v2e_w2 = (const float*)d_in[12];
    const float* v2e_b2 = (const float*)d_in[13];
    const float* e2v_w1 = (const float*)d_in[14];
    const float* e2v_b1 = (const float*)d_in[15];
    const float* e2v_w2 = (const float*)d_in[16];
    const float* e2v_b2 = (const float*)d_in[17];
    const float* hw1    = (const float*)d_in[18];
    const float* hb1    = (const float*)d_in[19];
    const float* hw2    = (const float*)d_in[20];
    const float* hb2    = (const float*)d_in[21];
    const float* scale  = (const float*)d_in[22];

    // stages: 0=ew2 1=w1he0 2=w2_0 3=u1_0 4=w1he1 5=w2_1 6=u1_1
    k_prep_w<<<112, 256, 0, stream>>>(ew2, v2e_w1 + 4096, v2e_w2, e2v_w1,
                                      v2e_w1 + 12288, v2e_w2 + 4096, e2v_w1 + 4096,
                                      WH, WL);
    k_node<<<8192, 64, 0, stream>>>(x, spin, nw1, nb1, nw2, nb2, hv0);
    k_p<<<8192, 64, 0, stream>>>(hv0, v2e_w1, v2e_b1, p0);
    k_L0<<<8192, 256, 0, stream>>>(x, ew1, eb1, eb2,
        p0, v2e_b2, e2v_b1, e2v_w2, e2v_b2,
        WH, WL, hv0, hv1, he0g);
    k_p<<<8192, 64, 0, stream>>>(hv1, v2e_w1 + 8192, v2e_b1 + 64, p1);
    k_L1<<<8192, 256, 0, stream>>>(he0g,
        p1, v2e_b2 + 64, e2v_b1 + 64, e2v_w2 + 4096, e2v_b2 + 64,
        WH, WL, hv1, hw1, hb1, hw2, hb2, scale, dx);
    k_mean<<<128, 64, 0, stream>>>(dx, (float*)d_out);
}

// Round 10
// 261.419 us; speedup vs baseline: 3.1198x; 1.2036x over previous
//
#include <hip/hip_runtime.h>
#include <math.h>

// B=128, N=64, D=2, H=64, M=64, L=2. f32 in / f32 out (beacon-verified R6; R7-R9 passed).
// R10: fp16 MFMA datapath (single mfma_f32_16x16x32_f16, f32 acc) replaces
// split-bf16 3-MFMA; one LDS tile; he0' stored as f16 (67MB); k_p fused into
// k_node and k_L0 tail. MFMA addressing identical to R9 (verified).

typedef unsigned short u16;
typedef unsigned int u32;
typedef _Float16 half8 __attribute__((ext_vector_type(8)));   // 4 VGPR frag
typedef __attribute__((ext_vector_type(4))) float floatx4;

#define TS 72   // tile row stride in f16 elems (144 B, 16B-aligned rows)

__device__ __forceinline__ float gelu_f(float x) {
    float u = x * 0.70710678118654752f;
    float s = fabsf(u);
    float t = __builtin_amdgcn_rcpf(fmaf(0.3275911f, s, 1.0f));
    float P = t * fmaf(t, fmaf(t, fmaf(t, fmaf(t, 1.061405429f, -1.453152027f),
                                        1.421413741f), -0.284496736f), 0.254829592f);
    float e = __expf(-s * s);
    float r = fmaf(-P, e, 1.0f);          // erf(|u|), max err 1.5e-7
    r = copysignf(r, u);
    return 0.5f * x * (1.0f + r);
}

// pack 7 stage-weights (64x64, row-major (k,n)) into B-frag order f16:
// off = (((s*2+kc)*64 + n)*4 + q)*8 + j  where k = kc*32 + q*8 + j   (R9-verified)
__global__ __launch_bounds__(256) void k_prep_w(
    const float* w0, const float* w1, const float* w2, const float* w3,
    const float* w4, const float* w5, const float* w6,
    _Float16* __restrict__ WF)
{
    int idx = blockIdx.x * 256 + threadIdx.x;
    if (idx >= 7 * 4096) return;
    int s = idx >> 12, r = idx & 4095, k = r >> 6, n = r & 63;
    const float* W = s==0?w0: s==1?w1: s==2?w2: s==3?w3: s==4?w4: s==5?w5: w6;
    int kc = k >> 5, q = (k >> 3) & 3, jj = k & 7;
    WF[(((s * 2 + kc) * 64 + n) * 4 + q) * 8 + jj] = (_Float16)W[k * 64 + n];
}

// wave computes out[0:64][c0:c0+16] of one 64x64 stage; acc[mt] = rows mt*16+quad*4+[0,4)
__device__ __forceinline__ void mfma_stage(
    const _Float16* __restrict__ tA, const _Float16* __restrict__ WF,
    int stage, int c, int quad, int nn, floatx4 acc[4])
{
    #pragma unroll
    for (int mt = 0; mt < 4; ++mt) acc[mt] = (floatx4){0.f, 0.f, 0.f, 0.f};
    int sA = ((nn >> 2) & 3) << 3;
    #pragma unroll
    for (int kc = 0; kc < 2; ++kc) {
        half8 bf = *(const half8*)(WF + (((stage * 2 + kc) * 64 + c) * 4 + quad) * 8);
        int k0 = (kc * 32 + quad * 8) ^ sA;
        #pragma unroll
        for (int mt = 0; mt < 4; ++mt) {
            half8 af = *(const half8*)(tA + (mt * 16 + nn) * TS + k0);
            acc[mt] = __builtin_amdgcn_mfma_f32_16x16x32_f16(af, bf, acc[mt], 0, 0, 0);
        }
    }
}

__global__ __launch_bounds__(256, 8) void k_L0(
    const float* __restrict__ x,
    const float* __restrict__ ew1, const float* __restrict__ eb1,
    const float* __restrict__ eb2,
    const float* __restrict__ p0, const float* __restrict__ b2_0,
    const float* __restrict__ c1_0,
    const float* __restrict__ u2_0, const float* __restrict__ c2_0,
    const _Float16* __restrict__ WF,
    const float* __restrict__ hv0, float* __restrict__ hv1,
    const float* __restrict__ w1n, const float* __restrict__ b1n,   // layer-1 node part
    float* __restrict__ p1,
    u16* __restrict__ he0g)
{
    __shared__ __align__(16) _Float16 tA[64 * TS];
    __shared__ float sgeo[256];
    __shared__ float sS[64];
    __shared__ float shv[64];
    int t = threadIdx.x, w = t >> 6, L = t & 63;
    int nn = L & 15, quad = L >> 4;
    int c = w * 16 + nn;
    int sW = quad << 3;
    int b = blockIdx.x >> 6, j = blockIdx.x & 63;

    if (t < 64) {
        float2 xi = ((const float2*)x)[b * 64 + t];
        float2 xj = ((const float2*)x)[b * 64 + j];
        float d0 = xj.x - xi.x, d1 = xj.y - xi.y;     // dr = x_j - x_i
        float r2 = fmaf(d0, d0, d1 * d1);
        sgeo[t] = d0; sgeo[64 + t] = d1; sgeo[128 + t] = sqrtf(r2 + 1e-12f); sgeo[192 + t] = r2;
    }
    __syncthreads();
    // g1[i][m] = gelu(feat(i) @ ew1 + eb1)
    for (int q = t; q < 4096; q += 256) {
        int i = q >> 6, m = q & 63;
        float z = fmaf(sgeo[i], ew1[m], fmaf(sgeo[64 + i], ew1[64 + m],
                  fmaf(sgeo[128 + i], ew1[128 + m], fmaf(sgeo[192 + i], ew1[192 + m], eb1[m]))));
        tA[i * TS + (m ^ (((i >> 2) & 3) << 3))] = (_Float16)gelu_f(z);
    }
    __syncthreads();

    floatx4 acc[4];
    // stage 0: he0 = g1 @ ew2 + eb2
    mfma_stage(tA, WF, 0, c, quad, nn, acc);
    __syncthreads();
    {
        float bc = eb2[c];
        int cw = c ^ sW;
        #pragma unroll
        for (int mt = 0; mt < 4; ++mt)
            #pragma unroll
            for (int r = 0; r < 4; ++r)
                tA[(mt * 16 + quad * 4 + r) * TS + cw] = (_Float16)(acc[mt][r] + bc);
    }
    __syncthreads();
    // stage 1: z0 = p0 + he0 @ w1he0 -> gelu
    mfma_stage(tA, WF, 1, c, quad, nn, acc);
    __syncthreads();
    {
        int cw = c ^ sW;
        #pragma unroll
        for (int mt = 0; mt < 4; ++mt)
            #pragma unroll
            for (int r = 0; r < 4; ++r) {
                int i = mt * 16 + quad * 4 + r;
                tA[i * TS + cw] = (_Float16)gelu_f(acc[mt][r] + p0[(b * 64 + i) * 64 + c]);
            }
    }
    __syncthreads();
    // stage 2: he0' = @ w2_0 + b2_0 ; store f16 (swizzled layout) for k_L1
    mfma_stage(tA, WF, 2, c, quad, nn, acc);
    __syncthreads();
    {
        float bc = b2_0[c];
        int cw = c ^ sW;
        u16* dst = he0g + (size_t)blockIdx.x * 4096;
        #pragma unroll
        for (int mt = 0; mt < 4; ++mt)
            #pragma unroll
            for (int r = 0; r < 4; ++r) {
                int i = mt * 16 + quad * 4 + r;
                _Float16 hv = (_Float16)(acc[mt][r] + bc);
                tA[i * TS + cw] = hv;
                dst[i * 64 + cw] = __builtin_bit_cast(u16, hv);
            }
    }
    __syncthreads();
    // stage 3: a = gelu(@ u1_0 + c1_0); masked i-sum -> sS
    mfma_stage(tA, WF, 3, c, quad, nn, acc);
    {
        float bc = c1_0[c];
        float s = 0.f;
        #pragma unroll
        for (int mt = 0; mt < 4; ++mt)
            #pragma unroll
            for (int r = 0; r < 4; ++r) {
                int i = mt * 16 + quad * 4 + r;
                float g = gelu_f(acc[mt][r] + bc);
                s += (i == j) ? 0.f : g;
            }
        s += __shfl_xor(s, 16);
        s += __shfl_xor(s, 32);
        if (quad == 0) sS[c] = s;
    }
    __syncthreads();
    if (t < 64) {
        float g = 0.f;
        for (int m = 0; m < 64; ++m) g = fmaf(sS[m], u2_0[m * 64 + t], g);
        int o = blockIdx.x * 64 + t;
        float hvv = hv0[o] + g * (1.0f / 63.0f) + c2_0[t];
        hv1[o] = hvv;
        shv[t] = hvv;                      // wave-synchronous (wave 0 only)
        float pa = b1n[t];
        for (int h = 0; h < 64; ++h) pa = fmaf(shv[h], w1n[h * 64 + t], pa);
        p1[o] = pa;                        // fused k_p (layer 1)
    }
}

__global__ __launch_bounds__(256, 8) void k_L1(
    const u16* __restrict__ he0g,
    const float* __restrict__ p1, const float* __restrict__ b2_1,
    const float* __restrict__ c1_1,
    const float* __restrict__ u2_1, const float* __restrict__ c2_1,
    const _Float16* __restrict__ WF,
    const float* __restrict__ hv1,
    const float* __restrict__ hw1, const float* __restrict__ hb1,
    const float* __restrict__ hw2, const float* __restrict__ hb2,
    const float* __restrict__ scale, float* __restrict__ dx)
{
    __shared__ __align__(16) _Float16 tA[64 * TS];
    __shared__ float sS[64];
    __shared__ float shv[64];
    int t = threadIdx.x, w = t >> 6, L = t & 63;
    int nn = L & 15, quad = L >> 4;
    int c = w * 16 + nn;
    int sW = quad << 3;
    int b = blockIdx.x >> 6, j = blockIdx.x & 63;

    {   // he0' load: global layout == LDS layout (pre-swizzled); u32 copies
        const u32* src = (const u32*)(he0g + (size_t)blockIdx.x * 4096);
        for (int qq = t; qq < 2048; qq += 256) {
            u32 v = src[qq];
            int i = qq >> 5, m2 = (qq & 31) * 2;
            *(u32*)((u16*)tA + i * TS + m2) = v;
        }
    }
    __syncthreads();

    floatx4 acc[4];
    // stage 4: z1 = p1 + he0' @ w1he1 -> gelu
    mfma_stage(tA, WF, 4, c, quad, nn, acc);
    __syncthreads();
    {
        int cw = c ^ sW;
        #pragma unroll
        for (int mt = 0; mt < 4; ++mt)
            #pragma unroll
            for (int r = 0; r < 4; ++r) {
                int i = mt * 16 + quad * 4 + r;
                tA[i * TS + cw] = (_Float16)gelu_f(acc[mt][r] + p1[(b * 64 + i) * 64 + c]);
            }
    }
    __syncthreads();
    // stage 5: he1 = @ w2_1 + b2_1
    mfma_stage(tA, WF, 5, c, quad, nn, acc);
    __syncthreads();
    {
        float bc = b2_1[c];
        int cw = c ^ sW;
        #pragma unroll
        for (int mt = 0; mt < 4; ++mt)
            #pragma unroll
            for (int r = 0; r < 4; ++r)
                tA[(mt * 16 + quad * 4 + r) * TS + cw] = (_Float16)(acc[mt][r] + bc);
    }
    __syncthreads();
    // stage 6: a = gelu(@ u1_1 + c1_1); masked i-sum -> sS
    mfma_stage(tA, WF, 6, c, quad, nn, acc);
    {
        float bc = c1_1[c];
        float s = 0.f;
        #pragma unroll
        for (int mt = 0; mt < 4; ++mt)
            #pragma unroll
            for (int r = 0; r < 4; ++r) {
                int i = mt * 16 + quad * 4 + r;
                float g = gelu_f(acc[mt][r] + bc);
                s += (i == j) ? 0.f : g;
            }
        s += __shfl_xor(s, 16);
        s += __shfl_xor(s, 32);
        if (quad == 0) sS[c] = s;
    }
    __syncthreads();
    if (t < 64) {
        float g = 0.f;
        for (int m = 0; m < 64; ++m) g = fmaf(sS[m], u2_1[m * 64 + t], g);
        float hv2 = hv1[blockIdx.x * 64 + t] + g * (1.0f / 63.0f) + c2_1[t];
        shv[t] = hv2;                        // wave-synchronous (wave 0 only)
        float a = hb1[t];
        for (int m = 0; m < 64; ++m) a = fmaf(shv[m], hw1[m * 64 + t], a);
        float t1 = tanhf(a);
        float d0 = t1 * hw2[t * 2], d1 = t1 * hw2[t * 2 + 1];
        #pragma unroll
        for (int off = 1; off <= 32; off <<= 1) { d0 += __shfl_xor(d0, off); d1 += __shfl_xor(d1, off); }
        if (t == 0) {
            float sp = log1pf(__expf(scale[0]));
            dx[blockIdx.x * 2 + 0] = (d0 + hb2[0]) * sp;
            dx[blockIdx.x * 2 + 1] = (d1 + hb2[1]) * sp;
        }
    }
}

// fused node MLP + p0. 4 nodes per 256-thread block; wave = node, lane = channel.
__global__ __launch_bounds__(256) void k_node(
    const float* __restrict__ x, const float* __restrict__ spin,
    const float* __restrict__ nw1, const float* __restrict__ nb1,
    const float* __restrict__ nw2, const float* __restrict__ nb2,
    const float* __restrict__ w1_0, const float* __restrict__ b1_0,
    float* __restrict__ hv, float* __restrict__ p0)
{
    __shared__ float a[4][64];
    __shared__ float shv[4][64];
    int w = threadIdx.x >> 6, h = threadIdx.x & 63;
    int node = blockIdx.x * 4 + w;
    float2 xv = ((const float2*)x)[node];
    float sp = spin[node];
    float z = fmaf(xv.x, nw1[h], fmaf(xv.y, nw1[64 + h], fmaf(sp, nw1[128 + h], nb1[h])));
    a[w][h] = gelu_f(z);                   // wave-synchronous slice
    float acc = nb2[h];
    for (int k = 0; k < 64; ++k) acc = fmaf(a[w][k], nw2[k * 64 + h], acc);
    hv[node * 64 + h] = acc;
    shv[w][h] = acc;
    float pa = b1_0[h];
    for (int k = 0; k < 64; ++k) pa = fmaf(shv[w][k], w1_0[k * 64 + h], pa);
    p0[node * 64 + h] = pa;
}

__global__ __launch_bounds__(64) void k_mean(
    const float* __restrict__ dx, float* __restrict__ out)
{
    __shared__ float s0[64], s1[64];
    int b = blockIdx.x, j = threadIdx.x;
    float2 d = ((const float2*)dx)[b * 64 + j];
    s0[j] = d.x; s1[j] = d.y;
    __syncthreads();
    float m0 = 0.f, m1 = 0.f;
    for (int q = 0; q < 64; ++q) { m0 += s0[q]; m1 += s1[q]; }
    ((float2*)out)[b * 64 + j] = make_float2(d.x - m0 * (1.0f / 64.0f), d.y - m1 * (1.0f / 64.0f));
}

__global__ void k_beacon(float* out, float code) { out[0] = code; }

extern "C" void kernel_launch(void* const* d_in, const int* in_sizes, int n_in,
                              void* d_out, int out_size, void* d_ws, size_t ws_size,
                              hipStream_t stream)
{
    static const int exp_sizes[23] = {
        16384, 8192, 192, 64, 4096, 64,
        256, 64, 4096, 64,
        16384, 128, 8192, 128,
        8192, 128, 8192, 128,
        4096, 64, 128, 2, 1
    };
    // ws layout
    float* hv0 = (float*)d_ws;                  // 524288 f
    float* hv1 = hv0 + 524288;
    float* p0  = hv1 + 524288;
    float* p1  = p0  + 524288;
    float* dx  = p1  + 524288;                  // 16384 f
    _Float16* WF = (_Float16*)(dx + 16384);     // 28672 f16
    u16* he0g  = (u16*)(WF + 28672);            // 33554432 u16 (67 MB)
    const size_t need = (size_t)((char*)(he0g + 33554432) - (char*)d_ws);

    int bad = -1;
    if (n_in != 23 || out_size != 16384) bad = 98;
    else if (ws_size < need) bad = 97;
    else for (int i = 0; i < 23; ++i)
        if (in_sizes[i] != exp_sizes[i]) { bad = i; break; }
    if (bad >= 0) {
        k_beacon<<<1, 1, 0, stream>>>((float*)d_out, 2e6f + bad * 1e4f);
        return;
    }

    const float* x      = (const float*)d_in[0];
    const float* spin   = (const float*)d_in[1];
    const float* nw1    = (const float*)d_in[2];
    const float* nb1    = (const float*)d_in[3];
    const float* nw2    = (const float*)d_in[4];
    const float* nb2    = (const float*)d_in[5];
    const float* ew1    = (const float*)d_in[6];
    const float* eb1    = (const float*)d_in[7];
    const float* ew2    = (const float*)d_in[8];
    const float* eb2    = (const float*)d_in[9];
    const float* v2e_w1 = (const float*)d_in[10];
    const float* v2e_b1 = (const float*)d_in[11];
    const float* v2e_w2 = (const float*)d_in[12];
    const float* v2e_b2 = (const float*)d_in[13];
    const float* e2v_w1 = (const float*)d_in[14];
    const float* e2v_b1 = (const float*)d_in[15];
    const float* e2v_w2 = (const float*)d_in[16];
    const float* e2v_b2 = (const float*)d_in[17];
    const float* hw1    = (const float*)d_in[18];
    const float* hb1    = (const float*)d_in[19];
    const float* hw2    = (const float*)d_in[20];
    const float* hb2    = (const float*)d_in[21];
    const float* scale  = (const float*)d_in[22];

    // stages: 0=ew2 1=w1he0 2=w2_0 3=u1_0 4=w1he1 5=w2_1 6=u1_1
    k_prep_w<<<112, 256, 0, stream>>>(ew2, v2e_w1 + 4096, v2e_w2, e2v_w1,
                                      v2e_w1 + 12288, v2e_w2 + 4096, e2v_w1 + 4096, WF);
    k_node<<<2048, 256, 0, stream>>>(x, spin, nw1, nb1, nw2, nb2,
                                     v2e_w1, v2e_b1, hv0, p0);
    k_L0<<<8192, 256, 0, stream>>>(x, ew1, eb1, eb2,
        p0, v2e_b2, e2v_b1, e2v_w2, e2v_b2,
        WF, hv0, hv1,
        v2e_w1 + 8192, v2e_b1 + 64, p1,
        he0g);
    k_L1<<<8192, 256, 0, stream>>>(he0g,
        p1, v2e_b2 + 64, e2v_b1 + 64, e2v_w2 + 4096, e2v_b2 + 64,
        WF, hv1, hw1, hb1, hw2, hb2, scale, dx);
    k_mean<<<128, 64, 0, stream>>>(dx, (float*)d_out);
}

// Round 11
// 256.020 us; speedup vs baseline: 3.1856x; 1.0211x over previous
//
#include <hip/hip_runtime.h>
#include <math.h>

// B=128, N=64, D=2, H=64, M=64, L=2. f32 in / f32 out (beacon-verified R6; R7-R10 passed).
// R11: pairwise gelu2 (packed-f32 SLP), bias/p folded into MFMA acc init,
// transposed aux weights for float4 tails, prep+node fused into one launch.
// MFMA fragment addressing identical to R9/R10 (verified).

typedef unsigned short u16;
typedef unsigned int u32;
typedef _Float16 half8 __attribute__((ext_vector_type(8)));   // 4 VGPR frag
typedef __attribute__((ext_vector_type(4))) float floatx4;

#define TS 72   // tile row stride in f16 elems (144 B, 16B-aligned rows)

__device__ __forceinline__ float2 gelu2(float2 x) {
    const float K = 0.70710678118654752f;
    float ux = x.x * K,        uy = x.y * K;
    float sx = fabsf(ux),      sy = fabsf(uy);
    float tx = __builtin_amdgcn_rcpf(fmaf(0.3275911f, sx, 1.0f));
    float ty = __builtin_amdgcn_rcpf(fmaf(0.3275911f, sy, 1.0f));
    float Px = tx * fmaf(tx, fmaf(tx, fmaf(tx, fmaf(tx, 1.061405429f, -1.453152027f),
                                           1.421413741f), -0.284496736f), 0.254829592f);
    float Py = ty * fmaf(ty, fmaf(ty, fmaf(ty, fmaf(ty, 1.061405429f, -1.453152027f),
                                           1.421413741f), -0.284496736f), 0.254829592f);
    float ex = __expf(-sx * sx);
    float ey = __expf(-sy * sy);
    float rx = copysignf(fmaf(-Px, ex, 1.0f), ux);
    float ry = copysignf(fmaf(-Py, ey, 1.0f), uy);
    return make_float2(0.5f * x.x * (1.0f + rx), 0.5f * x.y * (1.0f + ry));
}
__device__ __forceinline__ float gelu_f(float x) {
    float u = x * 0.70710678118654752f;
    float s = fabsf(u);
    float t = __builtin_amdgcn_rcpf(fmaf(0.3275911f, s, 1.0f));
    float P = t * fmaf(t, fmaf(t, fmaf(t, fmaf(t, 1.061405429f, -1.453152027f),
                                        1.421413741f), -0.284496736f), 0.254829592f);
    float r = copysignf(fmaf(-P, __expf(-s * s), 1.0f), u);
    return 0.5f * x * (1.0f + r);
}

// merged prep: [0,112) f16-pack 7 stage weights; [112,176) f32-transpose 4 aux;
// [176,2224) node MLP + p0 (4 nodes per block).
__global__ __launch_bounds__(256) void k_pre(
    const float* w0, const float* w1, const float* w2, const float* w3,
    const float* w4, const float* w5, const float* w6,
    const float* u2_0, const float* u2_1, const float* w1n, const float* hw1,
    _Float16* __restrict__ WF,
    float* __restrict__ u2_0T, float* __restrict__ u2_1T,
    float* __restrict__ w1nT, float* __restrict__ hw1T,
    const float* __restrict__ x, const float* __restrict__ spin,
    const float* __restrict__ nw1, const float* __restrict__ nb1,
    const float* __restrict__ nw2, const float* __restrict__ nb2,
    const float* __restrict__ w1_0, const float* __restrict__ b1_0,
    float* __restrict__ hv, float* __restrict__ p0)
{
    int blk = blockIdx.x;
    if (blk < 112) {
        int idx = blk * 256 + threadIdx.x;           // < 28672 = 7*4096
        int s = idx >> 12, r = idx & 4095, k = r >> 6, n = r & 63;
        const float* W = s==0?w0: s==1?w1: s==2?w2: s==3?w3: s==4?w4: s==5?w5: w6;
        int kc = k >> 5, q = (k >> 3) & 3, jj = k & 7;
        WF[(((s * 2 + kc) * 64 + n) * 4 + q) * 8 + jj] = (_Float16)W[k * 64 + n];
    } else if (blk < 176) {
        int idx = (blk - 112) * 256 + threadIdx.x;   // < 16384 = 4*4096
        int s = idx >> 12, r = idx & 4095, m = r >> 6, tc = r & 63;
        const float* W = s==0?u2_0: s==1?u2_1: s==2?w1n: hw1;
        float* WT      = s==0?u2_0T: s==1?u2_1T: s==2?w1nT: hw1T;
        WT[tc * 64 + m] = W[m * 64 + tc];
    } else {
        __shared__ float a[4][64];
        __shared__ float shv[4][64];
        int w = threadIdx.x >> 6, h = threadIdx.x & 63;
        int node = (blk - 176) * 4 + w;
        float2 xv = ((const float2*)x)[node];
        float sp = spin[node];
        float z = fmaf(xv.x, nw1[h], fmaf(xv.y, nw1[64 + h], fmaf(sp, nw1[128 + h], nb1[h])));
        a[w][h] = gelu_f(z);                         // wave-synchronous slice
        float acc = nb2[h];
        for (int k = 0; k < 64; ++k) acc = fmaf(a[w][k], nw2[k * 64 + h], acc);
        hv[node * 64 + h] = acc;
        shv[w][h] = acc;
        float pa = b1_0[h];
        for (int k = 0; k < 64; ++k) pa = fmaf(shv[w][k], w1_0[k * 64 + h], pa);
        p0[node * 64 + h] = pa;
    }
}

// accumulate one 64x64 stage into pre-initialized acc (R9-verified addressing)
__device__ __forceinline__ void mfma_acc(
    const _Float16* __restrict__ tA, const _Float16* __restrict__ WF,
    int stage, int c, int quad, int nn, floatx4 acc[4])
{
    int sA = ((nn >> 2) & 3) << 3;
    #pragma unroll
    for (int kc = 0; kc < 2; ++kc) {
        half8 bf = *(const half8*)(WF + (((stage * 2 + kc) * 64 + c) * 4 + quad) * 8);
        int k0 = (kc * 32 + quad * 8) ^ sA;
        #pragma unroll
        for (int mt = 0; mt < 4; ++mt) {
            half8 af = *(const half8*)(tA + (mt * 16 + nn) * TS + k0);
            acc[mt] = __builtin_amdgcn_mfma_f32_16x16x32_f16(af, bf, acc[mt], 0, 0, 0);
        }
    }
}

__device__ __forceinline__ void init_bias(floatx4 acc[4], float bc) {
    #pragma unroll
    for (int mt = 0; mt < 4; ++mt) acc[mt] = (floatx4){bc, bc, bc, bc};
}
__device__ __forceinline__ void init_p(floatx4 acc[4], const float* __restrict__ p,
                                       int rowbase, int c, int quad) {
    #pragma unroll
    for (int mt = 0; mt < 4; ++mt)
        #pragma unroll
        for (int r = 0; r < 4; ++r)
            acc[mt][r] = p[(rowbase + mt * 16 + quad * 4 + r) * 64 + c];
}

__global__ __launch_bounds__(256, 8) void k_L0(
    const float* __restrict__ x,
    const float* __restrict__ ew1, const float* __restrict__ eb1,
    const float* __restrict__ eb2,
    const float* __restrict__ p0, const float* __restrict__ b2_0,
    const float* __restrict__ c1_0,
    const float* __restrict__ u2_0T, const float* __restrict__ c2_0,
    const _Float16* __restrict__ WF,
    const float* __restrict__ hv0, float* __restrict__ hv1,
    const float* __restrict__ w1nT, const float* __restrict__ b1n,
    float* __restrict__ p1,
    u16* __restrict__ he0g)
{
    __shared__ __align__(16) _Float16 tA[64 * TS];
    __shared__ float sgeo[256];
    __shared__ float sS[64];
    __shared__ float shv[64];
    int t = threadIdx.x, w = t >> 6, L = t & 63;
    int nn = L & 15, quad = L >> 4;
    int c = w * 16 + nn;
    int cw = c ^ (quad << 3);
    int b = blockIdx.x >> 6, j = blockIdx.x & 63;

    if (t < 64) {
        float2 xi = ((const float2*)x)[b * 64 + t];
        float2 xj = ((const float2*)x)[b * 64 + j];
        float d0 = xj.x - xi.x, d1 = xj.y - xi.y;     // dr = x_j - x_i
        float r2 = fmaf(d0, d0, d1 * d1);
        sgeo[t] = d0; sgeo[64 + t] = d1; sgeo[128 + t] = sqrtf(r2 + 1e-12f); sgeo[192 + t] = r2;
    }
    __syncthreads();
    // g1[i][m] = gelu(feat(i) @ ew1 + eb1)  — m fixed per thread, pair i's
    {
        int m = t & 63, i0 = t >> 6;
        float wa = ew1[m], wb = ew1[64 + m], wc = ew1[128 + m], wd = ew1[192 + m], bm = eb1[m];
        #pragma unroll
        for (int k = 0; k < 16; k += 2) {
            int ia = i0 + k * 4, ib = i0 + (k + 1) * 4;
            float za = fmaf(sgeo[ia], wa, fmaf(sgeo[64 + ia], wb,
                       fmaf(sgeo[128 + ia], wc, fmaf(sgeo[192 + ia], wd, bm))));
            float zb = fmaf(sgeo[ib], wa, fmaf(sgeo[64 + ib], wb,
                       fmaf(sgeo[128 + ib], wc, fmaf(sgeo[192 + ib], wd, bm))));
            float2 g = gelu2(make_float2(za, zb));
            tA[ia * TS + (m ^ (((ia >> 2) & 3) << 3))] = (_Float16)g.x;
            tA[ib * TS + (m ^ (((ib >> 2) & 3) << 3))] = (_Float16)g.y;
        }
    }
    __syncthreads();

    floatx4 acc[4];
    // stage 0: he0 = g1 @ ew2 + eb2   (bias in acc init)
    init_bias(acc, eb2[c]);
    mfma_acc(tA, WF, 0, c, quad, nn, acc);
    __syncthreads();
    #pragma unroll
    for (int mt = 0; mt < 4; ++mt)
        #pragma unroll
        for (int r = 0; r < 4; ++r)
            tA[(mt * 16 + quad * 4 + r) * TS + cw] = (_Float16)acc[mt][r];
    __syncthreads();
    // stage 1: z0 = p0 + he0 @ w1he0 -> gelu   (p0 in acc init)
    init_p(acc, p0, b * 64, c, quad);
    mfma_acc(tA, WF, 1, c, quad, nn, acc);
    __syncthreads();
    #pragma unroll
    for (int mt = 0; mt < 4; ++mt)
        #pragma unroll
        for (int rp = 0; rp < 4; rp += 2) {
            float2 g = gelu2(make_float2(acc[mt][rp], acc[mt][rp + 1]));
            tA[(mt * 16 + quad * 4 + rp) * TS + cw]     = (_Float16)g.x;
            tA[(mt * 16 + quad * 4 + rp + 1) * TS + cw] = (_Float16)g.y;
        }
    __syncthreads();
    // stage 2: he0' = @ w2_0 + b2_0 ; store f16 (swizzled) for k_L1
    init_bias(acc, b2_0[c]);
    mfma_acc(tA, WF, 2, c, quad, nn, acc);
    __syncthreads();
    {
        u16* dst = he0g + (size_t)blockIdx.x * 4096;
        #pragma unroll
        for (int mt = 0; mt < 4; ++mt)
            #pragma unroll
            for (int r = 0; r < 4; ++r) {
                int i = mt * 16 + quad * 4 + r;
                _Float16 hvv = (_Float16)acc[mt][r];
                tA[i * TS + cw] = hvv;
                dst[i * 64 + cw] = __builtin_bit_cast(u16, hvv);
            }
    }
    __syncthreads();
    // stage 3: a = gelu(@ u1_0 + c1_0); masked i-sum -> sS
    init_bias(acc, c1_0[c]);
    mfma_acc(tA, WF, 3, c, quad, nn, acc);
    {
        float s = 0.f;
        #pragma unroll
        for (int mt = 0; mt < 4; ++mt)
            #pragma unroll
            for (int rp = 0; rp < 4; rp += 2) {
                int i = mt * 16 + quad * 4 + rp;
                float2 g = gelu2(make_float2(acc[mt][rp], acc[mt][rp + 1]));
                s += (i == j ? 0.f : g.x) + (i + 1 == j ? 0.f : g.y);
            }
        s += __shfl_xor(s, 16);
        s += __shfl_xor(s, 32);
        if (quad == 0) sS[c] = s;
    }
    __syncthreads();
    if (t < 64) {
        const float4* sv4 = (const float4*)sS;
        const float4* uv4 = (const float4*)(u2_0T + t * 64);
        float g = 0.f;
        #pragma unroll
        for (int m4 = 0; m4 < 16; ++m4) {
            float4 sv = sv4[m4], uv = uv4[m4];
            g = fmaf(sv.x, uv.x, fmaf(sv.y, uv.y, fmaf(sv.z, uv.z, fmaf(sv.w, uv.w, g))));
        }
        int o = blockIdx.x * 64 + t;
        float hvv = hv0[o] + g * (1.0f / 63.0f) + c2_0[t];
        hv1[o] = hvv;
        shv[t] = hvv;                      // wave-synchronous (wave 0 only)
        const float4* hv4 = (const float4*)shv;
        const float4* wv4 = (const float4*)(w1nT + t * 64);
        float pa = b1n[t];
        #pragma unroll
        for (int m4 = 0; m4 < 16; ++m4) {
            float4 sv = hv4[m4], uv = wv4[m4];
            pa = fmaf(sv.x, uv.x, fmaf(sv.y, uv.y, fmaf(sv.z, uv.z, fmaf(sv.w, uv.w, pa))));
        }
        p1[o] = pa;
    }
}

__global__ __launch_bounds__(256, 8) void k_L1(
    const u16* __restrict__ he0g,
    const float* __restrict__ p1, const float* __restrict__ b2_1,
    const float* __restrict__ c1_1,
    const float* __restrict__ u2_1T, const float* __restrict__ c2_1,
    const _Float16* __restrict__ WF,
    const float* __restrict__ hv1,
    const float* __restrict__ hw1T, const float* __restrict__ hb1,
    const float* __restrict__ hw2, const float* __restrict__ hb2,
    const float* __restrict__ scale, float* __restrict__ dx)
{
    __shared__ __align__(16) _Float16 tA[64 * TS];
    __shared__ float sS[64];
    __shared__ float shv[64];
    int t = threadIdx.x, w = t >> 6, L = t & 63;
    int nn = L & 15, quad = L >> 4;
    int c = w * 16 + nn;
    int cw = c ^ (quad << 3);
    int b = blockIdx.x >> 6, j = blockIdx.x & 63;

    {   // he0' load: global layout == LDS layout (pre-swizzled)
        const u32* src = (const u32*)(he0g + (size_t)blockIdx.x * 4096);
        for (int qq = t; qq < 2048; qq += 256) {
            u32 v = src[qq];
            int i = qq >> 5, m2 = (qq & 31) * 2;
            *(u32*)((u16*)tA + i * TS + m2) = v;
        }
    }
    __syncthreads();

    floatx4 acc[4];
    // stage 4: z1 = p1 + he0' @ w1he1 -> gelu
    init_p(acc, p1, b * 64, c, quad);
    mfma_acc(tA, WF, 4, c, quad, nn, acc);
    __syncthreads();
    #pragma unroll
    for (int mt = 0; mt < 4; ++mt)
        #pragma unroll
        for (int rp = 0; rp < 4; rp += 2) {
            float2 g = gelu2(make_float2(acc[mt][rp], acc[mt][rp + 1]));
            tA[(mt * 16 + quad * 4 + rp) * TS + cw]     = (_Float16)g.x;
            tA[(mt * 16 + quad * 4 + rp + 1) * TS + cw] = (_Float16)g.y;
        }
    __syncthreads();
    // stage 5: he1 = @ w2_1 + b2_1
    init_bias(acc, b2_1[c]);
    mfma_acc(tA, WF, 5, c, quad, nn, acc);
    __syncthreads();
    #pragma unroll
    for (int mt = 0; mt < 4; ++mt)
        #pragma unroll
        for (int r = 0; r < 4; ++r)
            tA[(mt * 16 + quad * 4 + r) * TS + cw] = (_Float16)acc[mt][r];
    __syncthreads();
    // stage 6: a = gelu(@ u1_1 + c1_1); masked i-sum -> sS
    init_bias(acc, c1_1[c]);
    mfma_acc(tA, WF, 6, c, quad, nn, acc);
    {
        float s = 0.f;
        #pragma unroll
        for (int mt = 0; mt < 4; ++mt)
            #pragma unroll
            for (int rp = 0; rp < 4; rp += 2) {
                int i = mt * 16 + quad * 4 + rp;
                float2 g = gelu2(make_float2(acc[mt][rp], acc[mt][rp + 1]));
                s += (i == j ? 0.f : g.x) + (i + 1 == j ? 0.f : g.y);
            }
        s += __shfl_xor(s, 16);
        s += __shfl_xor(s, 32);
        if (quad == 0) sS[c] = s;
    }
    __syncthreads();
    if (t < 64) {
        const float4* sv4 = (const float4*)sS;
        const float4* uv4 = (const float4*)(u2_1T + t * 64);
        float g = 0.f;
        #pragma unroll
        for (int m4 = 0; m4 < 16; ++m4) {
            float4 sv = sv4[m4], uv = uv4[m4];
            g = fmaf(sv.x, uv.x, fmaf(sv.y, uv.y, fmaf(sv.z, uv.z, fmaf(sv.w, uv.w, g))));
        }
        float hv2 = hv1[blockIdx.x * 64 + t] + g * (1.0f / 63.0f) + c2_1[t];
        shv[t] = hv2;                        // wave-synchronous (wave 0 only)
        const float4* hv4 = (const float4*)shv;
        const float4* wv4 = (const float4*)(hw1T + t * 64);
        float a = hb1[t];
        #pragma unroll
        for (int m4 = 0; m4 < 16; ++m4) {
            float4 sv = hv4[m4], uv = wv4[m4];
            a = fmaf(sv.x, uv.x, fmaf(sv.y, uv.y, fmaf(sv.z, uv.z, fmaf(sv.w, uv.w, a))));
        }
        float t1 = tanhf(a);
        float d0 = t1 * hw2[t * 2], d1 = t1 * hw2[t * 2 + 1];
        #pragma unroll
        for (int off = 1; off <= 32; off <<= 1) { d0 += __shfl_xor(d0, off); d1 += __shfl_xor(d1, off); }
        if (t == 0) {
            float sp = log1pf(__expf(scale[0]));
            dx[blockIdx.x * 2 + 0] = (d0 + hb2[0]) * sp;
            dx[blockIdx.x * 2 + 1] = (d1 + hb2[1]) * sp;
        }
    }
}

__global__ __launch_bounds__(64) void k_mean(
    const float* __restrict__ dx, float* __restrict__ out)
{
    __shared__ float s0[64], s1[64];
    int b = blockIdx.x, j = threadIdx.x;
    float2 d = ((const float2*)dx)[b * 64 + j];
    s0[j] = d.x; s1[j] = d.y;
    __syncthreads();
    float m0 = 0.f, m1 = 0.f;
    for (int q = 0; q < 64; ++q) { m0 += s0[q]; m1 += s1[q]; }
    ((float2*)out)[b * 64 + j] = make_float2(d.x - m0 * (1.0f / 64.0f), d.y - m1 * (1.0f / 64.0f));
}

__global__ void k_beacon(float* out, float code) { out[0] = code; }

extern "C" void kernel_launch(void* const* d_in, const int* in_sizes, int n_in,
                              void* d_out, int out_size, void* d_ws, size_t ws_size,
                              hipStream_t stream)
{
    static const int exp_sizes[23] = {
        16384, 8192, 192, 64, 4096, 64,
        256, 64, 4096, 64,
        16384, 128, 8192, 128,
        8192, 128, 8192, 128,
        4096, 64, 128, 2, 1
    };
    // ws layout
    float* hv0 = (float*)d_ws;                  // 524288 f
    float* hv1 = hv0 + 524288;
    float* p0  = hv1 + 524288;
    float* p1  = p0  + 524288;
    float* dx  = p1  + 524288;                  // 16384 f
    float* u2_0T = dx + 16384;                  // 4096 f
    float* u2_1T = u2_0T + 4096;
    float* w1nT  = u2_1T + 4096;
    float* hw1T  = w1nT + 4096;
    _Float16* WF = (_Float16*)(hw1T + 4096);    // 28672 f16
    u16* he0g  = (u16*)(WF + 28672);            // 33554432 u16 (67 MB)
    const size_t need = (size_t)((char*)(he0g + 33554432) - (char*)d_ws);

    int bad = -1;
    if (n_in != 23 || out_size != 16384) bad = 98;
    else if (ws_size < need) bad = 97;
    else for (int i = 0; i < 23; ++i)
        if (in_sizes[i] != exp_sizes[i]) { bad = i; break; }
    if (bad >= 0) {
        k_beacon<<<1, 1, 0, stream>>>((float*)d_out, 2e6f + bad * 1e4f);
        return;
    }

    const float* x      = (const float*)d_in[0];
    const float* spin   = (const float*)d_in[1];
    const float* nw1    = (const float*)d_in[2];
    const float* nb1    = (const float*)d_in[3];
    const float* nw2    = (const float*)d_in[4];
    const float* nb2    = (const float*)d_in[5];
    const float* ew1    = (const float*)d_in[6];
    const float* eb1    = (const float*)d_in[7];
    const float* ew2    = (const float*)d_in[8];
    const float* eb2    = (const float*)d_in[9];
    const float* v2e_w1 = (const float*)d_in[10];
    const float* v2e_b1 = (const float*)d_in[11];
    const float* v2e_w2 = (const float*)d_in[12];
    const float* v2e_b2 = (const float*)d_in[13];
    const float* e2v_w1 = (const float*)d_in[14];
    const float* e2v_b1 = (const float*)d_in[15];
    const float* e2v_w2 = (const float*)d_in[16];
    const float* e2v_b2 = (const float*)d_in[17];
    const float* hw1    = (const float*)d_in[18];
    const float* hb1    = (const float*)d_in[19];
    const float* hw2    = (const float*)d_in[20];
    const float* hb2    = (const float*)d_in[21];
    const float* scale  = (const float*)d_in[22];

    // stages: 0=ew2 1=w1he0 2=w2_0 3=u1_0 4=w1he1 5=w2_1 6=u1_1
    k_pre<<<2224, 256, 0, stream>>>(
        ew2, v2e_w1 + 4096, v2e_w2, e2v_w1, v2e_w1 + 12288, v2e_w2 + 4096, e2v_w1 + 4096,
        e2v_w2, e2v_w2 + 4096, v2e_w1 + 8192, hw1,
        WF, u2_0T, u2_1T, w1nT, hw1T,
        x, spin, nw1, nb1, nw2, nb2, v2e_w1, v2e_b1, hv0, p0);
    k_L0<<<8192, 256, 0, stream>>>(x, ew1, eb1, eb2,
        p0, v2e_b2, e2v_b1, u2_0T, e2v_b2,
        WF, hv0, hv1,
        w1nT, v2e_b1 + 64, p1,
        he0g);
    k_L1<<<8192, 256, 0, stream>>>(he0g,
        p1, v2e_b2 + 64, e2v_b1 + 64, u2_1T, e2v_b2 + 64,
        WF, hv1, hw1T, hb1, hw2, hb2, scale, dx);
    k_mean<<<128, 64, 0, stream>>>(dx, (float*)d_out);
}

// Round 12
// 243.605 us; speedup vs baseline: 3.3479x; 1.0510x over previous
//
#include <hip/hip_runtime.h>
#include <math.h>

// B=128, N=64, D=2, H=64, M=64, L=2. f32 in / f32 out (beacon-verified R6; R7-R11 passed).
// R12: exact linear-stage fusion. Merged weights (computed once in k_pre1):
//   SA = ew2@w1he0 (+biasA=eb2@w1he0, folded into p0')
//   SB = w2_0@u1_0 (+biasB=b2_0@u1_0+c1_0)
//   SC = w2_0@w1he1 (+biasC=b2_0@w1he1, folded into p1')
//   SD = w2_1@u1_1 (+biasD=b2_1@u1_1+c1_1)
// k_L0: g1 -> [M1: p0'+g1@SA] -> Y=gelu (stored to he0g) -> [M2: Y@SB+biasB]
//       -> gelu -> masked sum -> hv1, p1'
// k_L1: load Y -> [M3: p1'+Y@SC] -> gelu -> [M4: @SD+biasD] -> gelu -> sum -> head
// MFMA fragment addressing identical to R9-R11 (verified).

typedef unsigned short u16;
typedef unsigned int u32;
typedef _Float16 half8 __attribute__((ext_vector_type(8)));   // 4 VGPR frag
typedef __attribute__((ext_vector_type(4))) float floatx4;

#define TS 72   // tile row stride in f16 elems (144 B, 16B-aligned rows)

__device__ __forceinline__ float gelu_f(float x) {
    float u = x * 0.70710678118654752f;
    float s = fabsf(u);
    float t = __builtin_amdgcn_rcpf(fmaf(0.3275911f, s, 1.0f));
    float P = t * fmaf(t, fmaf(t, fmaf(t, fmaf(t, 1.061405429f, -1.453152027f),
                                        1.421413741f), -0.284496736f), 0.254829592f);
    float r = copysignf(fmaf(-P, __expf(-s * s), 1.0f), u);
    return 0.5f * x * (1.0f + r);
}

// k_pre1: blocks [0,64): 4 merged 64x64 products -> WF f16 frag layout;
//         block 64: 4 bias vectors; blocks [65,129): 4 f32 transposes.
__global__ __launch_bounds__(256) void k_pre1(
    const float* __restrict__ ew2, const float* __restrict__ w1he0,
    const float* __restrict__ w2_0, const float* __restrict__ u1_0,
    const float* __restrict__ w1he1, const float* __restrict__ w2_1,
    const float* __restrict__ u1_1,
    const float* __restrict__ eb2, const float* __restrict__ b2_0,
    const float* __restrict__ c1_0, const float* __restrict__ b2_1,
    const float* __restrict__ c1_1,
    const float* __restrict__ u2_0, const float* __restrict__ u2_1,
    const float* __restrict__ w1n, const float* __restrict__ hw1,
    _Float16* __restrict__ WF,
    float* __restrict__ biasA, float* __restrict__ biasB,
    float* __restrict__ biasC, float* __restrict__ biasD,
    float* __restrict__ u2_0T, float* __restrict__ u2_1T,
    float* __restrict__ w1nT, float* __restrict__ hw1T)
{
    int blk = blockIdx.x;
    if (blk < 64) {
        int s = blk >> 4;                               // product id
        int idx = (blk & 15) * 256 + threadIdx.x;       // 0..4095
        int k = idx >> 6, n = idx & 63;
        const float *A, *Bm;
        if (s == 0)      { A = ew2;  Bm = w1he0; }
        else if (s == 1) { A = w2_0; Bm = u1_0;  }
        else if (s == 2) { A = w2_0; Bm = w1he1; }
        else             { A = w2_1; Bm = u1_1;  }
        float acc = 0.f;
        for (int q = 0; q < 64; ++q) acc = fmaf(A[k * 64 + q], Bm[q * 64 + n], acc);
        int kc = k >> 5, qd = (k >> 3) & 3, jj = k & 7;
        WF[(((s * 2 + kc) * 64 + n) * 4 + qd) * 8 + jj] = (_Float16)acc;
    } else if (blk == 64) {
        int s = threadIdx.x >> 6, cc = threadIdx.x & 63;
        const float *bv, *Bm, *add; float* dst;
        if (s == 0)      { bv = eb2;  Bm = w1he0; add = nullptr; dst = biasA; }
        else if (s == 1) { bv = b2_0; Bm = u1_0;  add = c1_0;    dst = biasB; }
        else if (s == 2) { bv = b2_0; Bm = w1he1; add = nullptr; dst = biasC; }
        else             { bv = b2_1; Bm = u1_1;  add = c1_1;    dst = biasD; }
        float acc = add ? add[cc] : 0.f;
        for (int q = 0; q < 64; ++q) acc = fmaf(bv[q], Bm[q * 64 + cc], acc);
        dst[cc] = acc;
    } else {
        int idx = (blk - 65) * 256 + threadIdx.x;       // 0..16383
        int s = idx >> 12, r = idx & 4095, m = r >> 6, tc = r & 63;
        const float* W = s == 0 ? u2_0 : s == 1 ? u2_1 : s == 2 ? w1n : hw1;
        float* WT      = s == 0 ? u2_0T : s == 1 ? u2_1T : s == 2 ? w1nT : hw1T;
        WT[tc * 64 + m] = W[m * 64 + tc];
    }
}

// k_pre2: node MLP + p0' (biasA folded). 4 nodes per 256-thread block.
__global__ __launch_bounds__(256) void k_pre2(
    const float* __restrict__ x, const float* __restrict__ spin,
    const float* __restrict__ nw1, const float* __restrict__ nb1,
    const float* __restrict__ nw2, const float* __restrict__ nb2,
    const float* __restrict__ w1_0, const float* __restrict__ b1_0,
    const float* __restrict__ biasA,
    float* __restrict__ hv, float* __restrict__ p0)
{
    __shared__ float a[4][64];
    __shared__ float shv[4][64];
    int w = threadIdx.x >> 6, h = threadIdx.x & 63;
    int node = blockIdx.x * 4 + w;
    float2 xv = ((const float2*)x)[node];
    float sp = spin[node];
    float z = fmaf(xv.x, nw1[h], fmaf(xv.y, nw1[64 + h], fmaf(sp, nw1[128 + h], nb1[h])));
    a[w][h] = gelu_f(z);                         // wave-synchronous slice
    float acc = nb2[h];
    for (int k = 0; k < 64; ++k) acc = fmaf(a[w][k], nw2[k * 64 + h], acc);
    hv[node * 64 + h] = acc;
    shv[w][h] = acc;
    float pa = b1_0[h] + biasA[h];
    for (int k = 0; k < 64; ++k) pa = fmaf(shv[w][k], w1_0[k * 64 + h], pa);
    p0[node * 64 + h] = pa;
}

// accumulate one 64x64 stage into pre-initialized acc (R9-verified addressing)
__device__ __forceinline__ void mfma_acc(
    const _Float16* __restrict__ tA, const _Float16* __restrict__ WF,
    int stage, int c, int quad, int nn, floatx4 acc[4])
{
    int sA = ((nn >> 2) & 3) << 3;
    #pragma unroll
    for (int kc = 0; kc < 2; ++kc) {
        half8 bf = *(const half8*)(WF + (((stage * 2 + kc) * 64 + c) * 4 + quad) * 8);
        int k0 = (kc * 32 + quad * 8) ^ sA;
        #pragma unroll
        for (int mt = 0; mt < 4; ++mt) {
            half8 af = *(const half8*)(tA + (mt * 16 + nn) * TS + k0);
            acc[mt] = __builtin_amdgcn_mfma_f32_16x16x32_f16(af, bf, acc[mt], 0, 0, 0);
        }
    }
}

__device__ __forceinline__ void init_bias(floatx4 acc[4], float bc) {
    #pragma unroll
    for (int mt = 0; mt < 4; ++mt) acc[mt] = (floatx4){bc, bc, bc, bc};
}
__device__ __forceinline__ void init_p(floatx4 acc[4], const float* __restrict__ p,
                                       int rowbase, int c, int quad) {
    #pragma unroll
    for (int mt = 0; mt < 4; ++mt)
        #pragma unroll
        for (int r = 0; r < 4; ++r)
            acc[mt][r] = p[(rowbase + mt * 16 + quad * 4 + r) * 64 + c];
}

__global__ __launch_bounds__(256, 8) void k_L0(
    const float* __restrict__ x,
    const float* __restrict__ ew1, const float* __restrict__ eb1,
    const float* __restrict__ p0,        // p0' (biasA folded)
    const float* __restrict__ biasB,
    const float* __restrict__ u2_0T, const float* __restrict__ c2_0,
    const _Float16* __restrict__ WF,
    const float* __restrict__ hv0, float* __restrict__ hv1,
    const float* __restrict__ w1nT, const float* __restrict__ b1n,
    const float* __restrict__ biasC,
    float* __restrict__ p1,
    u16* __restrict__ he0g)
{
    __shared__ __align__(16) _Float16 tA[64 * TS];
    __shared__ float sgeo[256];
    __shared__ float sS[64];
    __shared__ float shv[64];
    int t = threadIdx.x, w = t >> 6, L = t & 63;
    int nn = L & 15, quad = L >> 4;
    int c = w * 16 + nn;
    int cw = c ^ (quad << 3);
    int b = blockIdx.x >> 6, j = blockIdx.x & 63;

    if (t < 64) {
        float2 xi = ((const float2*)x)[b * 64 + t];
        float2 xj = ((const float2*)x)[b * 64 + j];
        float d0 = xj.x - xi.x, d1 = xj.y - xi.y;     // dr = x_j - x_i
        float r2 = fmaf(d0, d0, d1 * d1);
        sgeo[t] = d0; sgeo[64 + t] = d1; sgeo[128 + t] = sqrtf(r2 + 1e-12f); sgeo[192 + t] = r2;
    }
    __syncthreads();
    // g1[i][m] = gelu(feat(i) @ ew1 + eb1)
    {
        int m = t & 63, i0 = t >> 6;
        float wa = ew1[m], wb = ew1[64 + m], wc = ew1[128 + m], wd = ew1[192 + m], bm = eb1[m];
        #pragma unroll
        for (int k = 0; k < 16; ++k) {
            int i = i0 + k * 4;
            float z = fmaf(sgeo[i], wa, fmaf(sgeo[64 + i], wb,
                      fmaf(sgeo[128 + i], wc, fmaf(sgeo[192 + i], wd, bm))));
            tA[i * TS + (m ^ (((i >> 2) & 3) << 3))] = (_Float16)gelu_f(z);
        }
    }
    __syncthreads();

    floatx4 acc[4];
    // M1: z0 = p0' + g1 @ SA -> Y = gelu; store Y to LDS + he0g
    init_p(acc, p0, b * 64, c, quad);
    mfma_acc(tA, WF, 0, c, quad, nn, acc);
    __syncthreads();
    {
        u16* dst = he0g + (size_t)blockIdx.x * 4096;
        #pragma unroll
        for (int mt = 0; mt < 4; ++mt)
            #pragma unroll
            for (int r = 0; r < 4; ++r) {
                int i = mt * 16 + quad * 4 + r;
                _Float16 y = (_Float16)gelu_f(acc[mt][r]);
                tA[i * TS + cw] = y;
                dst[i * 64 + cw] = __builtin_bit_cast(u16, y);
            }
    }
    __syncthreads();
    // M2: a = gelu(Y @ SB + biasB); masked i-sum -> sS
    init_bias(acc, biasB[c]);
    mfma_acc(tA, WF, 1, c, quad, nn, acc);
    {
        float s = 0.f;
        #pragma unroll
        for (int mt = 0; mt < 4; ++mt)
            #pragma unroll
            for (int r = 0; r < 4; ++r) {
                int i = mt * 16 + quad * 4 + r;
                float g = gelu_f(acc[mt][r]);
                s += (i == j) ? 0.f : g;
            }
        s += __shfl_xor(s, 16);
        s += __shfl_xor(s, 32);
        if (quad == 0) sS[c] = s;
    }
    __syncthreads();
    if (t < 64) {
        const float4* sv4 = (const float4*)sS;
        const float4* uv4 = (const float4*)(u2_0T + t * 64);
        float g = 0.f;
        #pragma unroll
        for (int m4 = 0; m4 < 16; ++m4) {
            float4 sv = sv4[m4], uv = uv4[m4];
            g = fmaf(sv.x, uv.x, fmaf(sv.y, uv.y, fmaf(sv.z, uv.z, fmaf(sv.w, uv.w, g))));
        }
        int o = blockIdx.x * 64 + t;
        float hvv = hv0[o] + g * (1.0f / 63.0f) + c2_0[t];
        hv1[o] = hvv;
        shv[t] = hvv;                      // wave-synchronous (wave 0 only)
        const float4* hv4 = (const float4*)shv;
        const float4* wv4 = (const float4*)(w1nT + t * 64);
        float pa = b1n[t] + biasC[t];      // p1' (biasC folded)
        #pragma unroll
        for (int m4 = 0; m4 < 16; ++m4) {
            float4 sv = hv4[m4], uv = wv4[m4];
            pa = fmaf(sv.x, uv.x, fmaf(sv.y, uv.y, fmaf(sv.z, uv.z, fmaf(sv.w, uv.w, pa))));
        }
        p1[o] = pa;
    }
}

__global__ __launch_bounds__(256, 8) void k_L1(
    const u16* __restrict__ he0g,
    const float* __restrict__ p1,        // p1' (biasC folded)
    const float* __restrict__ biasD,
    const float* __restrict__ u2_1T, const float* __restrict__ c2_1,
    const _Float16* __restrict__ WF,
    const float* __restrict__ hv1,
    const float* __restrict__ hw1T, const float* __restrict__ hb1,
    const float* __restrict__ hw2, const float* __restrict__ hb2,
    const float* __restrict__ scale, float* __restrict__ dx)
{
    __shared__ __align__(16) _Float16 tA[64 * TS];
    __shared__ float sS[64];
    __shared__ float shv[64];
    int t = threadIdx.x, w = t >> 6, L = t & 63;
    int nn = L & 15, quad = L >> 4;
    int c = w * 16 + nn;
    int cw = c ^ (quad << 3);
    int b = blockIdx.x >> 6, j = blockIdx.x & 63;

    {   // Y load: global layout == LDS layout (pre-swizzled; R10-verified)
        const u32* src = (const u32*)(he0g + (size_t)blockIdx.x * 4096);
        for (int qq = t; qq < 2048; qq += 256) {
            u32 v = src[qq];
            int i = qq >> 5, m2 = (qq & 31) * 2;
            *(u32*)((u16*)tA + i * TS + m2) = v;
        }
    }
    __syncthreads();

    floatx4 acc[4];
    // M3: z1 = p1' + Y @ SC -> Y2 = gelu
    init_p(acc, p1, b * 64, c, quad);
    mfma_acc(tA, WF, 2, c, quad, nn, acc);
    __syncthreads();
    #pragma unroll
    for (int mt = 0; mt < 4; ++mt)
        #pragma unroll
        for (int r = 0; r < 4; ++r)
            tA[(mt * 16 + quad * 4 + r) * TS + cw] = (_Float16)gelu_f(acc[mt][r]);
    __syncthreads();
    // M4: a = gelu(Y2 @ SD + biasD); masked i-sum -> sS
    init_bias(acc, biasD[c]);
    mfma_acc(tA, WF, 3, c, quad, nn, acc);
    {
        float s = 0.f;
        #pragma unroll
        for (int mt = 0; mt < 4; ++mt)
            #pragma unroll
            for (int r = 0; r < 4; ++r) {
                int i = mt * 16 + quad * 4 + r;
                float g = gelu_f(acc[mt][r]);
                s += (i == j) ? 0.f : g;
            }
        s += __shfl_xor(s, 16);
        s += __shfl_xor(s, 32);
        if (quad == 0) sS[c] = s;
    }
    __syncthreads();
    if (t < 64) {
        const float4* sv4 = (const float4*)sS;
        const float4* uv4 = (const float4*)(u2_1T + t * 64);
        float g = 0.f;
        #pragma unroll
        for (int m4 = 0; m4 < 16; ++m4) {
            float4 sv = sv4[m4], uv = uv4[m4];
            g = fmaf(sv.x, uv.x, fmaf(sv.y, uv.y, fmaf(sv.z, uv.z, fmaf(sv.w, uv.w, g))));
        }
        float hv2 = hv1[blockIdx.x * 64 + t] + g * (1.0f / 63.0f) + c2_1[t];
        shv[t] = hv2;                        // wave-synchronous (wave 0 only)
        const float4* hv4 = (const float4*)shv;
        const float4* wv4 = (const float4*)(hw1T + t * 64);
        float a = hb1[t];
        #pragma unroll
        for (int m4 = 0; m4 < 16; ++m4) {
            float4 sv = hv4[m4], uv = wv4[m4];
            a = fmaf(sv.x, uv.x, fmaf(sv.y, uv.y, fmaf(sv.z, uv.z, fmaf(sv.w, uv.w, a))));
        }
        float t1 = tanhf(a);
        float d0 = t1 * hw2[t * 2], d1 = t1 * hw2[t * 2 + 1];
        #pragma unroll
        for (int off = 1; off <= 32; off <<= 1) { d0 += __shfl_xor(d0, off); d1 += __shfl_xor(d1, off); }
        if (t == 0) {
            float sp = log1pf(__expf(scale[0]));
            dx[blockIdx.x * 2 + 0] = (d0 + hb2[0]) * sp;
            dx[blockIdx.x * 2 + 1] = (d1 + hb2[1]) * sp;
        }
    }
}

__global__ __launch_bounds__(64) void k_mean(
    const float* __restrict__ dx, float* __restrict__ out)
{
    __shared__ float s0[64], s1[64];
    int b = blockIdx.x, j = threadIdx.x;
    float2 d = ((const float2*)dx)[b * 64 + j];
    s0[j] = d.x; s1[j] = d.y;
    __syncthreads();
    float m0 = 0.f, m1 = 0.f;
    for (int q = 0; q < 64; ++q) { m0 += s0[q]; m1 += s1[q]; }
    ((float2*)out)[b * 64 + j] = make_float2(d.x - m0 * (1.0f / 64.0f), d.y - m1 * (1.0f / 64.0f));
}

__global__ void k_beacon(float* out, float code) { out[0] = code; }

extern "C" void kernel_launch(void* const* d_in, const int* in_sizes, int n_in,
                              void* d_out, int out_size, void* d_ws, size_t ws_size,
                              hipStream_t stream)
{
    static const int exp_sizes[23] = {
        16384, 8192, 192, 64, 4096, 64,
        256, 64, 4096, 64,
        16384, 128, 8192, 128,
        8192, 128, 8192, 128,
        4096, 64, 128, 2, 1
    };
    // ws layout
    float* hv0 = (float*)d_ws;                  // 524288 f
    float* hv1 = hv0 + 524288;
    float* p0  = hv1 + 524288;
    float* p1  = p0  + 524288;
    float* dx  = p1  + 524288;                  // 16384 f
    float* u2_0T = dx + 16384;                  // 4096 f
    float* u2_1T = u2_0T + 4096;
    float* w1nT  = u2_1T + 4096;
    float* hw1T  = w1nT + 4096;
    float* biasA = hw1T + 4096;                 // 4 x 64 f
    float* biasB = biasA + 64;
    float* biasC = biasB + 64;
    float* biasD = biasC + 64;
    _Float16* WF = (_Float16*)(biasD + 64);     // 16384 f16 (4 stages)
    u16* he0g  = (u16*)(WF + 16384);            // 33554432 u16 (67 MB)
    const size_t need = (size_t)((char*)(he0g + 33554432) - (char*)d_ws);

    int bad = -1;
    if (n_in != 23 || out_size != 16384) bad = 98;
    else if (ws_size < need) bad = 97;
    else for (int i = 0; i < 23; ++i)
        if (in_sizes[i] != exp_sizes[i]) { bad = i; break; }
    if (bad >= 0) {
        k_beacon<<<1, 1, 0, stream>>>((float*)d_out, 2e6f + bad * 1e4f);
        return;
    }

    const float* x      = (const float*)d_in[0];
    const float* spin   = (const float*)d_in[1];
    const float* nw1    = (const float*)d_in[2];
    const float* nb1    = (const float*)d_in[3];
    const float* nw2    = (const float*)d_in[4];
    const float* nb2    = (const float*)d_in[5];
    const float* ew1    = (const float*)d_in[6];
    const float* eb1    = (const float*)d_in[7];
    const float* ew2    = (const float*)d_in[8];
    const float* eb2    = (const float*)d_in[9];
    const float* v2e_w1 = (const float*)d_in[10];
    const float* v2e_b1 = (const float*)d_in[11];
    const float* v2e_w2 = (const float*)d_in[12];
    const float* v2e_b2 = (const float*)d_in[13];
    const float* e2v_w1 = (const float*)d_in[14];
    const float* e2v_b1 = (const float*)d_in[15];
    const float* e2v_w2 = (const float*)d_in[16];
    const float* e2v_b2 = (const float*)d_in[17];
    const float* hw1    = (const float*)d_in[18];
    const float* hb1    = (const float*)d_in[19];
    const float* hw2    = (const float*)d_in[20];
    const float* hb2    = (const float*)d_in[21];
    const float* scale  = (const float*)d_in[22];

    // layer slices: w1he_l = v2e_w1 + l*8192 + 4096 (edge part); w1n_l = v2e_w1 + l*8192
    k_pre1<<<129, 256, 0, stream>>>(
        ew2, v2e_w1 + 4096, v2e_w2, e2v_w1,
        v2e_w1 + 12288, v2e_w2 + 4096, e2v_w1 + 4096,
        eb2, v2e_b2, e2v_b1, v2e_b2 + 64, e2v_b1 + 64,
        e2v_w2, e2v_w2 + 4096, v2e_w1 + 8192, hw1,
        WF, biasA, biasB, biasC, biasD,
        u2_0T, u2_1T, w1nT, hw1T);
    k_pre2<<<2048, 256, 0, stream>>>(x, spin, nw1, nb1, nw2, nb2,
                                     v2e_w1, v2e_b1, biasA, hv0, p0);
    k_L0<<<8192, 256, 0, stream>>>(x, ew1, eb1,
        p0, biasB, u2_0T, e2v_b2,
        WF, hv0, hv1,
        w1nT, v2e_b1 + 64, biasC, p1,
        he0g);
    k_L1<<<8192, 256, 0, stream>>>(he0g,
        p1, biasD, u2_1T, e2v_b2 + 64,
        WF, hv1, hw1T, hb1, hw2, hb2, scale, dx);
    k_mean<<<128, 64, 0, stream>>>(dx, (float*)d_out);
}

// Round 13
// 227.313 us; speedup vs baseline: 3.5879x; 1.0717x over previous
//
#include <hip/hip_runtime.h>
#include <math.h>

// B=128, N=64, D=2, H=64, M=64, L=2. f32 in / f32 out (beacon-verified R6; R7-R12 passed).
// R13: g1 stage lane=i (SGPR weights, half8 packed LDS writes), parallel tails,
// Hastings 3-term erf, he0g padded to 72 for linear float4 Y-copy.
// Merged weights (k_pre1): SA=ew2@w1he0, SB=w2_0@u1_0(+biasB), SC=w2_0@w1he1,
// SD=w2_1@u1_1(+biasD); biasA'=eb2@w1he0+b1_0, biasC'=b2_0@w1he1+b1n.
// MFMA fragment addressing identical to R9-R12 (verified).

typedef unsigned short u16;
typedef unsigned int u32;
typedef _Float16 half8 __attribute__((ext_vector_type(8)));   // 4 VGPR frag
typedef __attribute__((ext_vector_type(4))) float floatx4;

#define TS 72            // LDS tile row stride (f16): 144 B
#define HROW 72          // he0g row stride (u16) — mirrors LDS tile
#define HBLK (64 * HROW) // 4608 u16 per block

__device__ __forceinline__ float gelu_f(float x) {
    float u = x * 0.70710678118654752f;
    float s = fabsf(u);
    float t = __builtin_amdgcn_rcpf(fmaf(0.47047f, s, 1.0f));
    float P = t * fmaf(t, fmaf(t, 0.7478556f, -0.0958798f), 0.3480242f);  // A&S 7.1.25
    float r = copysignf(fmaf(-P, __expf(-s * s), 1.0f), u);
    return 0.5f * x * (1.0f + r);
}

// k_pre1: blocks [0,64): 4 merged 64x64 products -> WF f16 frag layout;
//         block 64: 4 bias vectors (with folds); blocks [65,129): 4 f32 transposes.
__global__ __launch_bounds__(256) void k_pre1(
    const float* __restrict__ ew2, const float* __restrict__ w1he0,
    const float* __restrict__ w2_0, const float* __restrict__ u1_0,
    const float* __restrict__ w1he1, const float* __restrict__ w2_1,
    const float* __restrict__ u1_1,
    const float* __restrict__ eb2, const float* __restrict__ b2_0,
    const float* __restrict__ c1_0, const float* __restrict__ b2_1,
    const float* __restrict__ c1_1,
    const float* __restrict__ b1_0v, const float* __restrict__ b1nv,
    const float* __restrict__ u2_0, const float* __restrict__ u2_1,
    const float* __restrict__ w1n, const float* __restrict__ hw1,
    _Float16* __restrict__ WF,
    float* __restrict__ biasA, float* __restrict__ biasB,
    float* __restrict__ biasC, float* __restrict__ biasD,
    float* __restrict__ u2_0T, float* __restrict__ u2_1T,
    float* __restrict__ w1nT, float* __restrict__ hw1T)
{
    int blk = blockIdx.x;
    if (blk < 64) {
        int s = blk >> 4;                               // product id
        int idx = (blk & 15) * 256 + threadIdx.x;       // 0..4095
        int k = idx >> 6, n = idx & 63;
        const float *A, *Bm;
        if (s == 0)      { A = ew2;  Bm = w1he0; }
        else if (s == 1) { A = w2_0; Bm = u1_0;  }
        else if (s == 2) { A = w2_0; Bm = w1he1; }
        else             { A = w2_1; Bm = u1_1;  }
        float acc = 0.f;
        for (int q = 0; q < 64; ++q) acc = fmaf(A[k * 64 + q], Bm[q * 64 + n], acc);
        int kc = k >> 5, qd = (k >> 3) & 3, jj = k & 7;
        WF[(((s * 2 + kc) * 64 + n) * 4 + qd) * 8 + jj] = (_Float16)acc;
    } else if (blk == 64) {
        int s = threadIdx.x >> 6, cc = threadIdx.x & 63;
        const float *bv, *Bm, *add; float* dst;
        if (s == 0)      { bv = eb2;  Bm = w1he0; add = b1_0v; dst = biasA; }
        else if (s == 1) { bv = b2_0; Bm = u1_0;  add = c1_0;  dst = biasB; }
        else if (s == 2) { bv = b2_0; Bm = w1he1; add = b1nv;  dst = biasC; }
        else             { bv = b2_1; Bm = u1_1;  add = c1_1;  dst = biasD; }
        float acc = add[cc];
        for (int q = 0; q < 64; ++q) acc = fmaf(bv[q], Bm[q * 64 + cc], acc);
        dst[cc] = acc;
    } else {
        int idx = (blk - 65) * 256 + threadIdx.x;       // 0..16383
        int s = idx >> 12, r = idx & 4095, m = r >> 6, tc = r & 63;
        const float* W = s == 0 ? u2_0 : s == 1 ? u2_1 : s == 2 ? w1n : hw1;
        float* WT      = s == 0 ? u2_0T : s == 1 ? u2_1T : s == 2 ? w1nT : hw1T;
        WT[tc * 64 + m] = W[m * 64 + tc];
    }
}

// k_pre2: node MLP + p0' (biasA' carries b1_0 + eb2@w1he0 fold). 4 nodes/block.
__global__ __launch_bounds__(256) void k_pre2(
    const float* __restrict__ x, const float* __restrict__ spin,
    const float* __restrict__ nw1, const float* __restrict__ nb1,
    const float* __restrict__ nw2, const float* __restrict__ nb2,
    const float* __restrict__ w1_0,
    const float* __restrict__ biasA,
    float* __restrict__ hv, float* __restrict__ p0)
{
    __shared__ float a[4][64];
    __shared__ float shv[4][64];
    int w = threadIdx.x >> 6, h = threadIdx.x & 63;
    int node = blockIdx.x * 4 + w;
    float2 xv = ((const float2*)x)[node];
    float sp = spin[node];
    float z = fmaf(xv.x, nw1[h], fmaf(xv.y, nw1[64 + h], fmaf(sp, nw1[128 + h], nb1[h])));
    a[w][h] = gelu_f(z);                         // wave-synchronous slice
    float acc = nb2[h];
    for (int k = 0; k < 64; ++k) acc = fmaf(a[w][k], nw2[k * 64 + h], acc);
    hv[node * 64 + h] = acc;
    shv[w][h] = acc;
    float pa = biasA[h];
    for (int k = 0; k < 64; ++k) pa = fmaf(shv[w][k], w1_0[k * 64 + h], pa);
    p0[node * 64 + h] = pa;
}

// accumulate one 64x64 stage into pre-initialized acc (R9-verified addressing)
__device__ __forceinline__ void mfma_acc(
    const _Float16* __restrict__ tA, const _Float16* __restrict__ WF,
    int stage, int c, int quad, int nn, floatx4 acc[4])
{
    int sA = ((nn >> 2) & 3) << 3;
    #pragma unroll
    for (int kc = 0; kc < 2; ++kc) {
        half8 bf = *(const half8*)(WF + (((stage * 2 + kc) * 64 + c) * 4 + quad) * 8);
        int k0 = (kc * 32 + quad * 8) ^ sA;
        #pragma unroll
        for (int mt = 0; mt < 4; ++mt) {
            half8 af = *(const half8*)(tA + (mt * 16 + nn) * TS + k0);
            acc[mt] = __builtin_amdgcn_mfma_f32_16x16x32_f16(af, bf, acc[mt], 0, 0, 0);
        }
    }
}

__device__ __forceinline__ void init_bias(floatx4 acc[4], float bc) {
    #pragma unroll
    for (int mt = 0; mt < 4; ++mt) acc[mt] = (floatx4){bc, bc, bc, bc};
}
__device__ __forceinline__ void init_p(floatx4 acc[4], const float* __restrict__ p,
                                       int rowbase, int c, int quad) {
    #pragma unroll
    for (int mt = 0; mt < 4; ++mt)
        #pragma unroll
        for (int r = 0; r < 4; ++r)
            acc[mt][r] = p[(rowbase + mt * 16 + quad * 4 + r) * 64 + c];
}

__global__ __launch_bounds__(256, 8) void k_L0(
    const float* __restrict__ x,
    const float* __restrict__ ew1, const float* __restrict__ eb1,
    const float* __restrict__ p0,        // p0' (biasA' folded)
    const float* __restrict__ biasB,
    const float* __restrict__ u2_0T, const float* __restrict__ c2_0,
    const _Float16* __restrict__ WF,
    const float* __restrict__ hv0, float* __restrict__ hv1,
    const float* __restrict__ w1nT, const float* __restrict__ biasC,
    float* __restrict__ p1,
    u16* __restrict__ he0g)
{
    __shared__ __align__(16) _Float16 tA[64 * TS];
    __shared__ float sS[64];
    __shared__ float shv[64];
    __shared__ float sred[256];
    int t = threadIdx.x, L = t & 63;
    int w = __builtin_amdgcn_readfirstlane(t >> 6);
    int nn = L & 15, quad = L >> 4;
    int c = w * 16 + nn;
    int cw = c ^ (quad << 3);
    int b = blockIdx.x >> 6, j = blockIdx.x & 63;

    // geometry in registers: lane = i = L
    float2 xi = ((const float2*)x)[b * 64 + L];
    float2 xj = ((const float2*)x)[b * 64 + j];
    float d0 = xj.x - xi.x, d1 = xj.y - xi.y;     // dr = x_j - x_i
    float r2 = fmaf(d0, d0, d1 * d1);
    float rr = sqrtf(r2 + 1e-12f);
    int swL = ((L >> 2) & 3) << 3;

    // g1 row L, m in [w*16, w*16+16): SGPR weights, packed b128 writes
    #pragma unroll
    for (int mb = 0; mb < 2; ++mb) {
        int m0 = w * 16 + mb * 8;
        half8 h8;
        #pragma unroll
        for (int kk = 0; kk < 8; ++kk) {
            int m = m0 + kk;
            float z = fmaf(d0, ew1[m], fmaf(d1, ew1[64 + m],
                      fmaf(rr, ew1[128 + m], fmaf(r2, ew1[192 + m], eb1[m]))));
            h8[kk] = (_Float16)gelu_f(z);
        }
        *(half8*)(tA + L * TS + (m0 ^ swL)) = h8;
    }
    __syncthreads();

    floatx4 acc[4];
    // M1: z0 = p0' + g1 @ SA -> Y = gelu; store Y to LDS + he0g (row stride 72)
    init_p(acc, p0, b * 64, c, quad);
    mfma_acc(tA, WF, 0, c, quad, nn, acc);
    __syncthreads();
    {
        u16* dst = he0g + (size_t)blockIdx.x * HBLK;
        #pragma unroll
        for (int mt = 0; mt < 4; ++mt)
            #pragma unroll
            for (int r = 0; r < 4; ++r) {
                int i = mt * 16 + quad * 4 + r;
                _Float16 y = (_Float16)gelu_f(acc[mt][r]);
                tA[i * TS + cw] = y;
                dst[i * HROW + cw] = __builtin_bit_cast(u16, y);
            }
    }
    __syncthreads();
    // M2: a = gelu(Y @ SB + biasB); masked i-sum -> sS
    init_bias(acc, biasB[c]);
    mfma_acc(tA, WF, 1, c, quad, nn, acc);
    {
        float s = 0.f;
        #pragma unroll
        for (int mt = 0; mt < 4; ++mt)
            #pragma unroll
            for (int r = 0; r < 4; ++r) {
                int i = mt * 16 + quad * 4 + r;
                float g = gelu_f(acc[mt][r]);
                s += (i == j) ? 0.f : g;
            }
        s += __shfl_xor(s, 16);
        s += __shfl_xor(s, 32);
        if (quad == 0) sS[c] = s;
    }
    __syncthreads();
    // tail phase A: hv1 (parallel over 256)
    {
        const float4* sv4 = (const float4*)(sS + w * 16);
        const float4* uv4 = (const float4*)(u2_0T + L * 64 + w * 16);
        float g = 0.f;
        #pragma unroll
        for (int m4 = 0; m4 < 4; ++m4) {
            float4 sv = sv4[m4], uv = uv4[m4];
            g = fmaf(sv.x, uv.x, fmaf(sv.y, uv.y, fmaf(sv.z, uv.z, fmaf(sv.w, uv.w, g))));
        }
        sred[w * 64 + L] = g;
    }
    __syncthreads();
    if (t < 64) {
        float g = sred[t] + sred[64 + t] + sred[128 + t] + sred[192 + t];
        int o = blockIdx.x * 64 + t;
        float hvv = hv0[o] + g * (1.0f / 63.0f) + c2_0[t];
        hv1[o] = hvv;
        shv[t] = hvv;
    }
    __syncthreads();
    // tail phase B: p1' (parallel over 256)
    {
        const float4* hv4 = (const float4*)(shv + w * 16);
        const float4* wv4 = (const float4*)(w1nT + L * 64 + w * 16);
        float pa = 0.f;
        #pragma unroll
        for (int m4 = 0; m4 < 4; ++m4) {
            float4 sv = hv4[m4], uv = wv4[m4];
            pa = fmaf(sv.x, uv.x, fmaf(sv.y, uv.y, fmaf(sv.z, uv.z, fmaf(sv.w, uv.w, pa))));
        }
        sred[w * 64 + L] = pa;
    }
    __syncthreads();
    if (t < 64)
        p1[blockIdx.x * 64 + t] = biasC[t] + sred[t] + sred[64 + t] + sred[128 + t] + sred[192 + t];
}

__global__ __launch_bounds__(256, 8) void k_L1(
    const u16* __restrict__ he0g,
    const float* __restrict__ p1,        // p1' (biasC' folded)
    const float* __restrict__ biasD,
    const float* __restrict__ u2_1T, const float* __restrict__ c2_1,
    const _Float16* __restrict__ WF,
    const float* __restrict__ hv1,
    const float* __restrict__ hw1T, const float* __restrict__ hb1,
    const float* __restrict__ hw2, const float* __restrict__ hb2,
    const float* __restrict__ scale, float* __restrict__ dx)
{
    __shared__ __align__(16) _Float16 tA[64 * TS];
    __shared__ float sS[64];
    __shared__ float shv[64];
    __shared__ float sred[256];
    int t = threadIdx.x, L = t & 63;
    int w = __builtin_amdgcn_readfirstlane(t >> 6);
    int nn = L & 15, quad = L >> 4;
    int c = w * 16 + nn;
    int cw = c ^ (quad << 3);
    int b = blockIdx.x >> 6, j = blockIdx.x & 63;

    {   // Y load: he0g layout mirrors LDS tile exactly -> linear float4 copy
        const float4* src = (const float4*)(he0g + (size_t)blockIdx.x * HBLK);
        float4* dstl = (float4*)tA;
        for (int q = t; q < (HBLK * 2 / 16); q += 256)   // 576 chunks
            dstl[q] = src[q];
    }
    __syncthreads();

    floatx4 acc[4];
    // M3: z1 = p1' + Y @ SC -> Y2 = gelu
    init_p(acc, p1, b * 64, c, quad);
    mfma_acc(tA, WF, 2, c, quad, nn, acc);
    __syncthreads();
    #pragma unroll
    for (int mt = 0; mt < 4; ++mt)
        #pragma unroll
        for (int r = 0; r < 4; ++r)
            tA[(mt * 16 + quad * 4 + r) * TS + cw] = (_Float16)gelu_f(acc[mt][r]);
    __syncthreads();
    // M4: a = gelu(Y2 @ SD + biasD); masked i-sum -> sS
    init_bias(acc, biasD[c]);
    mfma_acc(tA, WF, 3, c, quad, nn, acc);
    {
        float s = 0.f;
        #pragma unroll
        for (int mt = 0; mt < 4; ++mt)
            #pragma unroll
            for (int r = 0; r < 4; ++r) {
                int i = mt * 16 + quad * 4 + r;
                float g = gelu_f(acc[mt][r]);
                s += (i == j) ? 0.f : g;
            }
        s += __shfl_xor(s, 16);
        s += __shfl_xor(s, 32);
        if (quad == 0) sS[c] = s;
    }
    __syncthreads();
    // tail phase A: hv2
    {
        const float4* sv4 = (const float4*)(sS + w * 16);
        const float4* uv4 = (const float4*)(u2_1T + L * 64 + w * 16);
        float g = 0.f;
        #pragma unroll
        for (int m4 = 0; m4 < 4; ++m4) {
            float4 sv = sv4[m4], uv = uv4[m4];
            g = fmaf(sv.x, uv.x, fmaf(sv.y, uv.y, fmaf(sv.z, uv.z, fmaf(sv.w, uv.w, g))));
        }
        sred[w * 64 + L] = g;
    }
    __syncthreads();
    if (t < 64) {
        float g = sred[t] + sred[64 + t] + sred[128 + t] + sred[192 + t];
        float hv2 = hv1[blockIdx.x * 64 + t] + g * (1.0f / 63.0f) + c2_1[t];
        shv[t] = hv2;
    }
    __syncthreads();
    // tail phase B: head layer-1 (parallel) -> tanh
    {
        const float4* hv4 = (const float4*)(shv + w * 16);
        const float4* wv4 = (const float4*)(hw1T + L * 64 + w * 16);
        float a = 0.f;
        #pragma unroll
        for (int m4 = 0; m4 < 4; ++m4) {
            float4 sv = hv4[m4], uv = wv4[m4];
            a = fmaf(sv.x, uv.x, fmaf(sv.y, uv.y, fmaf(sv.z, uv.z, fmaf(sv.w, uv.w, a))));
        }
        sred[w * 64 + L] = a;
    }
    __syncthreads();
    if (t < 64) {
        float a = hb1[t] + sred[t] + sred[64 + t] + sred[128 + t] + sred[192 + t];
        sS[t] = tanhf(a);                 // st1 (sS dead, reuse)
    }
    __syncthreads();
    if (t < 64) {
        float t1 = sS[t];
        float dd0 = t1 * hw2[t * 2], dd1 = t1 * hw2[t * 2 + 1];
        #pragma unroll
        for (int off = 1; off <= 32; off <<= 1) { dd0 += __shfl_xor(dd0, off); dd1 += __shfl_xor(dd1, off); }
        if (t == 0) {
            float sp = log1pf(__expf(scale[0]));
            dx[blockIdx.x * 2 + 0] = (dd0 + hb2[0]) * sp;
            dx[blockIdx.x * 2 + 1] = (dd1 + hb2[1]) * sp;
        }
    }
}

__global__ __launch_bounds__(64) void k_mean(
    const float* __restrict__ dx, float* __restrict__ out)
{
    __shared__ float s0[64], s1[64];
    int b = blockIdx.x, j = threadIdx.x;
    float2 d = ((const float2*)dx)[b * 64 + j];
    s0[j] = d.x; s1[j] = d.y;
    __syncthreads();
    float m0 = 0.f, m1 = 0.f;
    for (int q = 0; q < 64; ++q) { m0 += s0[q]; m1 += s1[q]; }
    ((float2*)out)[b * 64 + j] = make_float2(d.x - m0 * (1.0f / 64.0f), d.y - m1 * (1.0f / 64.0f));
}

__global__ void k_beacon(float* out, float code) { out[0] = code; }

extern "C" void kernel_launch(void* const* d_in, const int* in_sizes, int n_in,
                              void* d_out, int out_size, void* d_ws, size_t ws_size,
                              hipStream_t stream)
{
    static const int exp_sizes[23] = {
        16384, 8192, 192, 64, 4096, 64,
        256, 64, 4096, 64,
        16384, 128, 8192, 128,
        8192, 128, 8192, 128,
        4096, 64, 128, 2, 1
    };
    // ws layout
    float* hv0 = (float*)d_ws;                  // 524288 f
    float* hv1 = hv0 + 524288;
    float* p0  = hv1 + 524288;
    float* p1  = p0  + 524288;
    float* dx  = p1  + 524288;                  // 16384 f
    float* u2_0T = dx + 16384;                  // 4096 f
    float* u2_1T = u2_0T + 4096;
    float* w1nT  = u2_1T + 4096;
    float* hw1T  = w1nT + 4096;
    float* biasA = hw1T + 4096;                 // 4 x 64 f
    float* biasB = biasA + 64;
    float* biasC = biasB + 64;
    float* biasD = biasC + 64;
    _Float16* WF = (_Float16*)(biasD + 64);     // 16384 f16 (4 stages)
    u16* he0g  = (u16*)(WF + 16384);            // 8192*4608 u16 (75.5 MB)
    const size_t need = (size_t)((char*)(he0g + (size_t)8192 * HBLK) - (char*)d_ws);

    int bad = -1;
    if (n_in != 23 || out_size != 16384) bad = 98;
    else if (ws_size < need) bad = 97;
    else for (int i = 0; i < 23; ++i)
        if (in_sizes[i] != exp_sizes[i]) { bad = i; break; }
    if (bad >= 0) {
        k_beacon<<<1, 1, 0, stream>>>((float*)d_out, 2e6f + bad * 1e4f);
        return;
    }

    const float* x      = (const float*)d_in[0];
    const float* spin   = (const float*)d_in[1];
    const float* nw1    = (const float*)d_in[2];
    const float* nb1    = (const float*)d_in[3];
    const float* nw2    = (const float*)d_in[4];
    const float* nb2    = (const float*)d_in[5];
    const float* ew1    = (const float*)d_in[6];
    const float* eb1    = (const float*)d_in[7];
    const float* ew2    = (const float*)d_in[8];
    const float* eb2    = (const float*)d_in[9];
    const float* v2e_w1 = (const float*)d_in[10];
    const float* v2e_b1 = (const float*)d_in[11];
    const float* v2e_w2 = (const float*)d_in[12];
    const float* v2e_b2 = (const float*)d_in[13];
    const float* e2v_w1 = (const float*)d_in[14];
    const float* e2v_b1 = (const float*)d_in[15];
    const float* e2v_w2 = (const float*)d_in[16];
    const float* e2v_b2 = (const float*)d_in[17];
    const float* hw1    = (const float*)d_in[18];
    const float* hb1    = (const float*)d_in[19];
    const float* hw2    = (const float*)d_in[20];
    const float* hb2    = (const float*)d_in[21];
    const float* scale  = (const float*)d_in[22];

    // layer slices: w1he_l = v2e_w1 + l*8192 + 4096 (edge part); w1n_l = v2e_w1 + l*8192
    k_pre1<<<129, 256, 0, stream>>>(
        ew2, v2e_w1 + 4096, v2e_w2, e2v_w1,
        v2e_w1 + 12288, v2e_w2 + 4096, e2v_w1 + 4096,
        eb2, v2e_b2, e2v_b1, v2e_b2 + 64, e2v_b1 + 64,
        v2e_b1, v2e_b1 + 64,
        e2v_w2, e2v_w2 + 4096, v2e_w1 + 8192, hw1,
        WF, biasA, biasB, biasC, biasD,
        u2_0T, u2_1T, w1nT, hw1T);
    k_pre2<<<2048, 256, 0, stream>>>(x, spin, nw1, nb1, nw2, nb2,
                                     v2e_w1, biasA, hv0, p0);
    k_L0<<<8192, 256, 0, stream>>>(x, ew1, eb1,
        p0, biasB, u2_0T, e2v_b2,
        WF, hv0, hv1,
        w1nT, biasC, p1,
        he0g);
    k_L1<<<8192, 256, 0, stream>>>(he0g,
        p1, biasD, u2_1T, e2v_b2 + 64,
        WF, hv1, hw1T, hb1, hw2, hb2, scale, dx);
    k_mean<<<128, 64, 0, stream>>>(dx, (float*)d_out);
}

// Round 14
// 226.899 us; speedup vs baseline: 3.5944x; 1.0018x over previous
//
#include <hip/hip_runtime.h>
#include <math.h>

// B=128, N=64, D=2, H=64, M=64, L=2. f32 in / f32 out (beacon-verified R6; R7-R13 passed).
// R14: exp-free rational erf (A&S 7.1.27, one rcp, branchless select);
// pre1+pre2 merged (biasA fold computed inline in the node part).
// Merged weights: SA=ew2@w1he0, SB=w2_0@u1_0(+biasB), SC=w2_0@w1he1, SD=w2_1@u1_1(+biasD);
// p0' carries b1_0+eb2@w1he0; p1' carries b1n+b2_0@w1he1 (biasC).
// MFMA fragment addressing identical to R9-R13 (verified).

typedef unsigned short u16;
typedef unsigned int u32;
typedef _Float16 half8 __attribute__((ext_vector_type(8)));   // 4 VGPR frag
typedef __attribute__((ext_vector_type(4))) float floatx4;

#define TS 72            // LDS tile row stride (f16): 144 B
#define HROW 72          // he0g row stride (u16) — mirrors LDS tile
#define HBLK (64 * HROW) // 4608 u16 per block

// gelu via A&S 7.1.27 rational erf (|eps_erf|<=5e-4), no exp:
//   s=|x|/sqrt2; q=1+a1 s+..+a4 s^4; r=q^-4 = 1-erf(s)
//   x>=0: gelu = x - 0.5 x r ;  x<0: gelu = 0.5 x r
__device__ __forceinline__ float gelu_f(float x) {
    float s = fabsf(x) * 0.70710678118654752f;
    float q = fmaf(fmaf(fmaf(fmaf(0.078108f, s, 0.000972f), s, 0.230389f), s, 0.278393f), s, 1.0f);
    float q2 = q * q;
    float r = __builtin_amdgcn_rcpf(q2 * q2);
    float t = 0.5f * x * r;
    return x > 0.f ? x - t : t;
}

// k_pre: blocks [0,64): 4 merged 64x64 products -> WF f16 frag layout;
//        block 64: bias vectors; blocks [65,129): 4 f32 transposes;
//        blocks [129,2177): node MLP + p0' (biasA fold inline), 4 nodes/block.
__global__ __launch_bounds__(256) void k_pre(
    const float* __restrict__ ew2, const float* __restrict__ w1he0,
    const float* __restrict__ w2_0, const float* __restrict__ u1_0,
    const float* __restrict__ w1he1, const float* __restrict__ w2_1,
    const float* __restrict__ u1_1,
    const float* __restrict__ eb2, const float* __restrict__ b2_0,
    const float* __restrict__ c1_0, const float* __restrict__ b2_1,
    const float* __restrict__ c1_1,
    const float* __restrict__ b1_0v, const float* __restrict__ b1nv,
    const float* __restrict__ u2_0, const float* __restrict__ u2_1,
    const float* __restrict__ w1n, const float* __restrict__ hw1,
    _Float16* __restrict__ WF,
    float* __restrict__ biasB, float* __restrict__ biasC, float* __restrict__ biasD,
    float* __restrict__ u2_0T, float* __restrict__ u2_1T,
    float* __restrict__ w1nT, float* __restrict__ hw1T,
    const float* __restrict__ x, const float* __restrict__ spin,
    const float* __restrict__ nw1, const float* __restrict__ nb1,
    const float* __restrict__ nw2, const float* __restrict__ nb2,
    const float* __restrict__ w1_0,
    float* __restrict__ hv, float* __restrict__ p0)
{
    int blk = blockIdx.x;
    if (blk < 64) {
        int s = blk >> 4;                               // product id
        int idx = (blk & 15) * 256 + threadIdx.x;       // 0..4095
        int k = idx >> 6, n = idx & 63;
        const float *A, *Bm;
        if (s == 0)      { A = ew2;  Bm = w1he0; }
        else if (s == 1) { A = w2_0; Bm = u1_0;  }
        else if (s == 2) { A = w2_0; Bm = w1he1; }
        else             { A = w2_1; Bm = u1_1;  }
        float acc = 0.f;
        for (int q = 0; q < 64; ++q) acc = fmaf(A[k * 64 + q], Bm[q * 64 + n], acc);
        int kc = k >> 5, qd = (k >> 3) & 3, jj = k & 7;
        WF[(((s * 2 + kc) * 64 + n) * 4 + qd) * 8 + jj] = (_Float16)acc;
    } else if (blk == 64) {
        int s = threadIdx.x >> 6, cc = threadIdx.x & 63;
        if (s > 0) {
            const float *bv, *Bm, *add; float* dst;
            if (s == 1)      { bv = b2_0; Bm = u1_0;  add = c1_0; dst = biasB; }
            else if (s == 2) { bv = b2_0; Bm = w1he1; add = b1nv; dst = biasC; }
            else             { bv = b2_1; Bm = u1_1;  add = c1_1; dst = biasD; }
            float acc = add[cc];
            for (int q = 0; q < 64; ++q) acc = fmaf(bv[q], Bm[q * 64 + cc], acc);
            dst[cc] = acc;
        }
    } else if (blk < 129) {
        int idx = (blk - 65) * 256 + threadIdx.x;       // 0..16383
        int s = idx >> 12, r = idx & 4095, m = r >> 6, tc = r & 63;
        const float* W = s == 0 ? u2_0 : s == 1 ? u2_1 : s == 2 ? w1n : hw1;
        float* WT      = s == 0 ? u2_0T : s == 1 ? u2_1T : s == 2 ? w1nT : hw1T;
        WT[tc * 64 + m] = W[m * 64 + tc];
    } else {
        __shared__ float a[4][64];
        __shared__ float shv[4][64];
        int w = threadIdx.x >> 6, h = threadIdx.x & 63;
        int node = (blk - 129) * 4 + w;
        float2 xv = ((const float2*)x)[node];
        float sp = spin[node];
        float z = fmaf(xv.x, nw1[h], fmaf(xv.y, nw1[64 + h], fmaf(sp, nw1[128 + h], nb1[h])));
        a[w][h] = gelu_f(z);                         // wave-synchronous slice
        float acc = nb2[h];
        for (int k = 0; k < 64; ++k) acc = fmaf(a[w][k], nw2[k * 64 + h], acc);
        hv[node * 64 + h] = acc;
        shv[w][h] = acc;
        // p0' = b1_0 + eb2@w1he0 (biasA fold, inline) + hv@w1_0
        float pa = b1_0v[h];
        for (int q = 0; q < 64; ++q) pa = fmaf(eb2[q], w1he0[q * 64 + h], pa);
        for (int k = 0; k < 64; ++k) pa = fmaf(shv[w][k], w1_0[k * 64 + h], pa);
        p0[node * 64 + h] = pa;
    }
}

// accumulate one 64x64 stage into pre-initialized acc (R9-verified addressing)
__device__ __forceinline__ void mfma_acc(
    const _Float16* __restrict__ tA, const _Float16* __restrict__ WF,
    int stage, int c, int quad, int nn, floatx4 acc[4])
{
    int sA = ((nn >> 2) & 3) << 3;
    #pragma unroll
    for (int kc = 0; kc < 2; ++kc) {
        half8 bf = *(const half8*)(WF + (((stage * 2 + kc) * 64 + c) * 4 + quad) * 8);
        int k0 = (kc * 32 + quad * 8) ^ sA;
        #pragma unroll
        for (int mt = 0; mt < 4; ++mt) {
            half8 af = *(const half8*)(tA + (mt * 16 + nn) * TS + k0);
            acc[mt] = __builtin_amdgcn_mfma_f32_16x16x32_f16(af, bf, acc[mt], 0, 0, 0);
        }
    }
}

__device__ __forceinline__ void init_bias(floatx4 acc[4], float bc) {
    #pragma unroll
    for (int mt = 0; mt < 4; ++mt) acc[mt] = (floatx4){bc, bc, bc, bc};
}
__device__ __forceinline__ void init_p(floatx4 acc[4], const float* __restrict__ p,
                                       int rowbase, int c, int quad) {
    #pragma unroll
    for (int mt = 0; mt < 4; ++mt)
        #pragma unroll
        for (int r = 0; r < 4; ++r)
            acc[mt][r] = p[(rowbase + mt * 16 + quad * 4 + r) * 64 + c];
}

__global__ __launch_bounds__(256, 8) void k_L0(
    const float* __restrict__ x,
    const float* __restrict__ ew1, const float* __restrict__ eb1,
    const float* __restrict__ p0,        // p0' (biasA folded)
    const float* __restrict__ biasB,
    const float* __restrict__ u2_0T, const float* __restrict__ c2_0,
    const _Float16* __restrict__ WF,
    const float* __restrict__ hv0, float* __restrict__ hv1,
    const float* __restrict__ w1nT, const float* __restrict__ biasC,
    float* __restrict__ p1,
    u16* __restrict__ he0g)
{
    __shared__ __align__(16) _Float16 tA[64 * TS];
    __shared__ float sS[64];
    __shared__ float shv[64];
    __shared__ float sred[256];
    int t = threadIdx.x, L = t & 63;
    int w = __builtin_amdgcn_readfirstlane(t >> 6);
    int nn = L & 15, quad = L >> 4;
    int c = w * 16 + nn;
    int cw = c ^ (quad << 3);
    int b = blockIdx.x >> 6, j = blockIdx.x & 63;

    // geometry in registers: lane = i = L
    float2 xi = ((const float2*)x)[b * 64 + L];
    float2 xj = ((const float2*)x)[b * 64 + j];
    float d0 = xj.x - xi.x, d1 = xj.y - xi.y;     // dr = x_j - x_i
    float r2 = fmaf(d0, d0, d1 * d1);
    float rr = sqrtf(r2 + 1e-12f);
    int swL = ((L >> 2) & 3) << 3;

    // g1 row L, m in [w*16, w*16+16): SGPR weights, packed b128 writes
    #pragma unroll
    for (int mb = 0; mb < 2; ++mb) {
        int m0 = w * 16 + mb * 8;
        half8 h8;
        #pragma unroll
        for (int kk = 0; kk < 8; ++kk) {
            int m = m0 + kk;
            float z = fmaf(d0, ew1[m], fmaf(d1, ew1[64 + m],
                      fmaf(rr, ew1[128 + m], fmaf(r2, ew1[192 + m], eb1[m]))));
            h8[kk] = (_Float16)gelu_f(z);
        }
        *(half8*)(tA + L * TS + (m0 ^ swL)) = h8;
    }
    __syncthreads();

    floatx4 acc[4];
    // M1: z0 = p0' + g1 @ SA -> Y = gelu; store Y to LDS + he0g (row stride 72)
    init_p(acc, p0, b * 64, c, quad);
    mfma_acc(tA, WF, 0, c, quad, nn, acc);
    __syncthreads();
    {
        u16* dst = he0g + (size_t)blockIdx.x * HBLK;
        #pragma unroll
        for (int mt = 0; mt < 4; ++mt)
            #pragma unroll
            for (int r = 0; r < 4; ++r) {
                int i = mt * 16 + quad * 4 + r;
                _Float16 y = (_Float16)gelu_f(acc[mt][r]);
                tA[i * TS + cw] = y;
                dst[i * HROW + cw] = __builtin_bit_cast(u16, y);
            }
    }
    __syncthreads();
    // M2: a = gelu(Y @ SB + biasB); masked i-sum -> sS
    init_bias(acc, biasB[c]);
    mfma_acc(tA, WF, 1, c, quad, nn, acc);
    {
        float s = 0.f;
        #pragma unroll
        for (int mt = 0; mt < 4; ++mt)
            #pragma unroll
            for (int r = 0; r < 4; ++r) {
                int i = mt * 16 + quad * 4 + r;
                float g = gelu_f(acc[mt][r]);
                s += (i == j) ? 0.f : g;
            }
        s += __shfl_xor(s, 16);
        s += __shfl_xor(s, 32);
        if (quad == 0) sS[c] = s;
    }
    __syncthreads();
    // tail phase A: hv1 (parallel over 256)
    {
        const float4* sv4 = (const float4*)(sS + w * 16);
        const float4* uv4 = (const float4*)(u2_0T + L * 64 + w * 16);
        float g = 0.f;
        #pragma unroll
        for (int m4 = 0; m4 < 4; ++m4) {
            float4 sv = sv4[m4], uv = uv4[m4];
            g = fmaf(sv.x, uv.x, fmaf(sv.y, uv.y, fmaf(sv.z, uv.z, fmaf(sv.w, uv.w, g))));
        }
        sred[w * 64 + L] = g;
    }
    __syncthreads();
    if (t < 64) {
        float g = sred[t] + sred[64 + t] + sred[128 + t] + sred[192 + t];
        int o = blockIdx.x * 64 + t;
        float hvv = hv0[o] + g * (1.0f / 63.0f) + c2_0[t];
        hv1[o] = hvv;
        shv[t] = hvv;
    }
    __syncthreads();
    // tail phase B: p1' (parallel over 256)
    {
        const float4* hv4 = (const float4*)(shv + w * 16);
        const float4* wv4 = (const float4*)(w1nT + L * 64 + w * 16);
        float pa = 0.f;
        #pragma unroll
        for (int m4 = 0; m4 < 4; ++m4) {
            float4 sv = hv4[m4], uv = wv4[m4];
            pa = fmaf(sv.x, uv.x, fmaf(sv.y, uv.y, fmaf(sv.z, uv.z, fmaf(sv.w, uv.w, pa))));
        }
        sred[w * 64 + L] = pa;
    }
    __syncthreads();
    if (t < 64)
        p1[blockIdx.x * 64 + t] = biasC[t] + sred[t] + sred[64 + t] + sred[128 + t] + sred[192 + t];
}

__global__ __launch_bounds__(256, 8) void k_L1(
    const u16* __restrict__ he0g,
    const float* __restrict__ p1,        // p1' (biasC folded)
    const float* __restrict__ biasD,
    const float* __restrict__ u2_1T, const float* __restrict__ c2_1,
    const _Float16* __restrict__ WF,
    const float* __restrict__ hv1,
    const float* __restrict__ hw1T, const float* __restrict__ hb1,
    const float* __restrict__ hw2, const float* __restrict__ hb2,
    const float* __restrict__ scale, float* __restrict__ dx)
{
    __shared__ __align__(16) _Float16 tA[64 * TS];
    __shared__ float sS[64];
    __shared__ float shv[64];
    __shared__ float sred[256];
    int t = threadIdx.x, L = t & 63;
    int w = __builtin_amdgcn_readfirstlane(t >> 6);
    int nn = L & 15, quad = L >> 4;
    int c = w * 16 + nn;
    int cw = c ^ (quad << 3);
    int b = blockIdx.x >> 6, j = blockIdx.x & 63;

    {   // Y load: he0g layout mirrors LDS tile exactly -> linear float4 copy
        const float4* src = (const float4*)(he0g + (size_t)blockIdx.x * HBLK);
        float4* dstl = (float4*)tA;
        for (int q = t; q < (HBLK * 2 / 16); q += 256)   // 576 chunks
            dstl[q] = src[q];
    }
    __syncthreads();

    floatx4 acc[4];
    // M3: z1 = p1' + Y @ SC -> Y2 = gelu
    init_p(acc, p1, b * 64, c, quad);
    mfma_acc(tA, WF, 2, c, quad, nn, acc);
    __syncthreads();
    #pragma unroll
    for (int mt = 0; mt < 4; ++mt)
        #pragma unroll
        for (int r = 0; r < 4; ++r)
            tA[(mt * 16 + quad * 4 + r) * TS + cw] = (_Float16)gelu_f(acc[mt][r]);
    __syncthreads();
    // M4: a = gelu(Y2 @ SD + biasD); masked i-sum -> sS
    init_bias(acc, biasD[c]);
    mfma_acc(tA, WF, 3, c, quad, nn, acc);
    {
        float s = 0.f;
        #pragma unroll
        for (int mt = 0; mt < 4; ++mt)
            #pragma unroll
            for (int r = 0; r < 4; ++r) {
                int i = mt * 16 + quad * 4 + r;
                float g = gelu_f(acc[mt][r]);
                s += (i == j) ? 0.f : g;
            }
        s += __shfl_xor(s, 16);
        s += __shfl_xor(s, 32);
        if (quad == 0) sS[c] = s;
    }
    __syncthreads();
    // tail phase A: hv2
    {
        const float4* sv4 = (const float4*)(sS + w * 16);
        const float4* uv4 = (const float4*)(u2_1T + L * 64 + w * 16);
        float g = 0.f;
        #pragma unroll
        for (int m4 = 0; m4 < 4; ++m4) {
            float4 sv = sv4[m4], uv = uv4[m4];
            g = fmaf(sv.x, uv.x, fmaf(sv.y, uv.y, fmaf(sv.z, uv.z, fmaf(sv.w, uv.w, g))));
        }
        sred[w * 64 + L] = g;
    }
    __syncthreads();
    if (t < 64) {
        float g = sred[t] + sred[64 + t] + sred[128 + t] + sred[192 + t];
        float hv2 = hv1[blockIdx.x * 64 + t] + g * (1.0f / 63.0f) + c2_1[t];
        shv[t] = hv2;
    }
    __syncthreads();
    // tail phase B: head layer-1 (parallel) -> tanh
    {
        const float4* hv4 = (const float4*)(shv + w * 16);
        const float4* wv4 = (const float4*)(hw1T + L * 64 + w * 16);
        float a = 0.f;
        #pragma unroll
        for (int m4 = 0; m4 < 4; ++m4) {
            float4 sv = hv4[m4], uv = wv4[m4];
            a = fmaf(sv.x, uv.x, fmaf(sv.y, uv.y, fmaf(sv.z, uv.z, fmaf(sv.w, uv.w, a))));
        }
        sred[w * 64 + L] = a;
    }
    __syncthreads();
    if (t < 64) {
        float a = hb1[t] + sred[t] + sred[64 + t] + sred[128 + t] + sred[192 + t];
        sS[t] = tanhf(a);                 // t1 (sS dead, reuse)
    }
    __syncthreads();
    if (t < 64) {
        float t1 = sS[t];
        float dd0 = t1 * hw2[t * 2], dd1 = t1 * hw2[t * 2 + 1];
        #pragma unroll
        for (int off = 1; off <= 32; off <<= 1) { dd0 += __shfl_xor(dd0, off); dd1 += __shfl_xor(dd1, off); }
        if (t == 0) {
            float sp = log1pf(__expf(scale[0]));
            dx[blockIdx.x * 2 + 0] = (dd0 + hb2[0]) * sp;
            dx[blockIdx.x * 2 + 1] = (dd1 + hb2[1]) * sp;
        }
    }
}

__global__ __launch_bounds__(64) void k_mean(
    const float* __restrict__ dx, float* __restrict__ out)
{
    __shared__ float s0[64], s1[64];
    int b = blockIdx.x, j = threadIdx.x;
    float2 d = ((const float2*)dx)[b * 64 + j];
    s0[j] = d.x; s1[j] = d.y;
    __syncthreads();
    float m0 = 0.f, m1 = 0.f;
    for (int q = 0; q < 64; ++q) { m0 += s0[q]; m1 += s1[q]; }
    ((float2*)out)[b * 64 + j] = make_float2(d.x - m0 * (1.0f / 64.0f), d.y - m1 * (1.0f / 64.0f));
}

__global__ void k_beacon(float* out, float code) { out[0] = code; }

extern "C" void kernel_launch(void* const* d_in, const int* in_sizes, int n_in,
                              void* d_out, int out_size, void* d_ws, size_t ws_size,
                              hipStream_t stream)
{
    static const int exp_sizes[23] = {
        16384, 8192, 192, 64, 4096, 64,
        256, 64, 4096, 64,
        16384, 128, 8192, 128,
        8192, 128, 8192, 128,
        4096, 64, 128, 2, 1
    };
    // ws layout
    float* hv0 = (float*)d_ws;                  // 524288 f
    float* hv1 = hv0 + 524288;
    float* p0  = hv1 + 524288;
    float* p1  = p0  + 524288;
    float* dx  = p1  + 524288;                  // 16384 f
    float* u2_0T = dx + 16384;                  // 4096 f
    float* u2_1T = u2_0T + 4096;
    float* w1nT  = u2_1T + 4096;
    float* hw1T  = w1nT + 4096;
    float* biasB = hw1T + 4096;                 // 3 x 64 f
    float* biasC = biasB + 64;
    float* biasD = biasC + 64;
    _Float16* WF = (_Float16*)(biasD + 64);     // 16384 f16 (4 stages)
    u16* he0g  = (u16*)(WF + 16384);            // 8192*4608 u16 (75.5 MB)
    const size_t need = (size_t)((char*)(he0g + (size_t)8192 * HBLK) - (char*)d_ws);

    int bad = -1;
    if (n_in != 23 || out_size != 16384) bad = 98;
    else if (ws_size < need) bad = 97;
    else for (int i = 0; i < 23; ++i)
        if (in_sizes[i] != exp_sizes[i]) { bad = i; break; }
    if (bad >= 0) {
        k_beacon<<<1, 1, 0, stream>>>((float*)d_out, 2e6f + bad * 1e4f);
        return;
    }

    const float* x      = (const float*)d_in[0];
    const float* spin   = (const float*)d_in[1];
    const float* nw1    = (const float*)d_in[2];
    const float* nb1    = (const float*)d_in[3];
    const float* nw2    = (const float*)d_in[4];
    const float* nb2    = (const float*)d_in[5];
    const float* ew1    = (const float*)d_in[6];
    const float* eb1    = (const float*)d_in[7];
    const float* ew2    = (const float*)d_in[8];
    const float* eb2    = (const float*)d_in[9];
    const float* v2e_w1 = (const float*)d_in[10];
    const float* v2e_b1 = (const float*)d_in[11];
    const float* v2e_w2 = (const float*)d_in[12];
    const float* v2e_b2 = (const float*)d_in[13];
    const float* e2v_w1 = (const float*)d_in[14];
    const float* e2v_b1 = (const float*)d_in[15];
    const float* e2v_w2 = (const float*)d_in[16];
    const float* e2v_b2 = (const float*)d_in[17];
    const float* hw1    = (const float*)d_in[18];
    const float* hb1    = (const float*)d_in[19];
    const float* hw2    = (const float*)d_in[20];
    const float* hb2    = (const float*)d_in[21];
    const float* scale  = (const float*)d_in[22];

    // layer slices: w1he_l = v2e_w1 + l*8192 + 4096 (edge part); w1n_l = v2e_w1 + l*8192
    k_pre<<<2177, 256, 0, stream>>>(
        ew2, v2e_w1 + 4096, v2e_w2, e2v_w1,
        v2e_w1 + 12288, v2e_w2 + 4096, e2v_w1 + 4096,
        eb2, v2e_b2, e2v_b1, v2e_b2 + 64, e2v_b1 + 64,
        v2e_b1, v2e_b1 + 64,
        e2v_w2, e2v_w2 + 4096, v2e_w1 + 8192, hw1,
        WF, biasB, biasC, biasD,
        u2_0T, u2_1T, w1nT, hw1T,
        x, spin, nw1, nb1, nw2, nb2, v2e_w1, hv0, p0);
    k_L0<<<8192, 256, 0, stream>>>(x, ew1, eb1,
        p0, biasB, u2_0T, e2v_b2,
        WF, hv0, hv1,
        w1nT, biasC, p1,
        he0g);
    k_L1<<<8192, 256, 0, stream>>>(he0g,
        p1, biasD, u2_1T, e2v_b2 + 64,
        WF, hv1, hw1T, hb1, hw2, hb2, scale, dx);
    k_mean<<<128, 64, 0, stream>>>(dx, (float*)d_out);
}